// Round 9
// baseline (525.613 us; speedup 1.0000x reference)
//
#include <hip/hip_runtime.h>

#define N_L 100000
#define N_V 1000
#define D_IN 64
#define HCH 64
#define D_OUT 32
#define E_LL 1000000

#define NCLS 8
#define DST_PER_CLS 12500        // N_L / 8
#define CLSCAP 131072            // class list capacity (mean 125000, +18 sigma)
#define GW 400                   // gather-bin node width
#define NSB 32                   // gather bins per class (31*400 + 100 = 12500)
#define NGSB 256                 // total gather bins = 1 block per CU
#define SUBCAP 4608              // per-bin pair capacity (mean 4000, +9.6 sigma)

#define L1CAP 768                // 8 class bins: no-reject (511 + 256 <= 767)
#define L1THR 512
#define L2CAP 384                // 32 sub bins: no-reject (127 + 256 <= 383)
#define L2THR 128
#define BINSUB_BPC 15            // binsub blocks per class

typedef unsigned int uint32;
typedef __attribute__((ext_vector_type(8))) short bfx8;    // 8 bf16 (4 VGPR)
typedef __attribute__((ext_vector_type(4))) float f32x4;   // MFMA C/D frag
typedef __attribute__((ext_vector_type(4))) float fvec4;
typedef __attribute__((ext_vector_type(4))) unsigned short usvec4;

__device__ inline float bf2f(unsigned short u) {
    return __uint_as_float(((uint32)u) << 16);
}
__device__ inline unsigned short f2bf(float f) {   // round-to-nearest-even
    uint32 u = __float_as_uint(f);
    u = (u + 0x7fffu + ((u >> 16) & 1u)) >> 16;
    return (unsigned short)u;
}

// ---- level-1: single edge scan; fused deg atomics; class-binned COO ------
// pack = (r << 14) | (c - cls*12500)   [r:17b, c_lo:14b]
__global__ __launch_bounds__(256) void binclass_kernel(
    const int* __restrict__ row, const int* __restrict__ col,
    int* __restrict__ deg, int* __restrict__ classcur,
    uint32* __restrict__ classpairs)
{
    __shared__ uint32 sbin[NCLS][L1CAP];
    __shared__ int scnt[NCLS];
    if (threadIdx.x < NCLS) scnt[threadIdx.x] = 0;
    __syncthreads();

    const int per = (E_LL + gridDim.x - 1) / gridDim.x;
    const int beg = blockIdx.x * per;
    const int end = (beg + per < E_LL) ? beg + per : E_LL;
    const int lane = threadIdx.x & 63;
    const int wv = threadIdx.x >> 6;

    for (int i0 = beg; i0 < end; i0 += 256) {
        int i = i0 + threadIdx.x;
        if (i < end) {
            int c = col[i];
            int r = row[i];
            atomicAdd(&deg[c], 1);
            int cls = c / DST_PER_CLS;
            uint32 pack = ((uint32)r << 14) | (uint32)(c - cls * DST_PER_CLS);
            int slot = atomicAdd(&scnt[cls], 1);   // < L1CAP guaranteed
            sbin[cls][slot] = pack;
        }
        __syncthreads();
        for (int b = wv; b < NCLS; b += 4) {
            int cnt = scnt[b];
            if (cnt >= L1THR) {
                int gb;
                if (lane == 0) gb = atomicAdd(&classcur[b], cnt);
                gb = __shfl(gb, 0);
                uint32* dst = classpairs + (size_t)b * CLSCAP;
                for (int k = lane; k < cnt; k += 64)
                    if (gb + k < CLSCAP) dst[gb + k] = sbin[b][k];
                if (lane == 0) scnt[b] = 0;
            }
        }
        __syncthreads();
    }
    for (int b = wv; b < NCLS; b += 4) {   // final flush
        int cnt = scnt[b];
        if (cnt > 0) {
            int gb;
            if (lane == 0) gb = atomicAdd(&classcur[b], cnt);
            gb = __shfl(gb, 0);
            uint32* dst = classpairs + (size_t)b * CLSCAP;
            for (int k = lane; k < cnt; k += 64)
                if (gb + k < CLSCAP) dst[gb + k] = sbin[b][k];
        }
    }
}

// ---- dinv[i] = deg>0 ? rsqrt(deg) : 0 ------------------------------------
__global__ void dinv_kernel(const int* __restrict__ deg,
                            float* __restrict__ dinv, int n) {
    int i = blockIdx.x * blockDim.x + threadIdx.x;
    if (i < n) {
        int d = deg[i];
        dinv[i] = (d > 0) ? rsqrtf((float)d) : 0.0f;
    }
}

// ---- xb[r,:] = bf16(x[r,:] * dinv[r]) ------------------------------------
__global__ void xbconv_kernel(const float* __restrict__ x,
                              const float* __restrict__ dinv,
                              unsigned short* __restrict__ xb) {
    int n4 = N_L * D_IN / 4;
    int idx = blockIdx.x * blockDim.x + threadIdx.x;
    int stride = gridDim.x * blockDim.x;
    for (; idx < n4; idx += stride) {
        fvec4 v = ((const fvec4*)x)[idx];
        float d = dinv[idx >> 4];
        usvec4 o;
        o.x = f2bf(v.x * d);
        o.y = f2bf(v.y * d);
        o.z = f2bf(v.z * d);
        o.w = f2bf(v.w * d);
        ((usvec4*)xb)[idx] = o;
    }
}

// ---- level-2: class COO -> 32 gather-bins per class ----------------------
// pack2 = (r << 9) | (c_lo - sb*400)   [r:17b, c_in_bin:9b]
__global__ __launch_bounds__(256) void binsub_kernel(
    const int* __restrict__ classcur, const uint32* __restrict__ classpairs,
    int* __restrict__ subcur, uint32* __restrict__ subpairs)
{
    __shared__ uint32 sbin[NSB][L2CAP];
    __shared__ int scnt[NSB];
    if (threadIdx.x < NSB) scnt[threadIdx.x] = 0;
    __syncthreads();

    const int cls = blockIdx.x / BINSUB_BPC;
    const int chunk = blockIdx.x % BINSUB_BPC;
    int len = classcur[cls]; if (len > CLSCAP) len = CLSCAP;
    const int beg = (int)((long long)len * chunk / BINSUB_BPC);
    const int end = (int)((long long)len * (chunk + 1) / BINSUB_BPC);
    const uint32* cp = classpairs + (size_t)cls * CLSCAP;
    const int lane = threadIdx.x & 63;
    const int wv = threadIdx.x >> 6;

    for (int i0 = beg; i0 < end; i0 += 256) {
        int i = i0 + threadIdx.x;
        if (i < end) {
            uint32 p = cp[i];
            int c_lo = (int)(p & 16383u);
            uint32 r = p >> 14;
            int sb = c_lo / GW;
            uint32 pack = (r << 9) | (uint32)(c_lo - sb * GW);
            int slot = atomicAdd(&scnt[sb], 1);    // < L2CAP guaranteed
            sbin[sb][slot] = pack;
        }
        __syncthreads();
        for (int b = wv; b < NSB; b += 4) {
            int cnt = scnt[b];
            if (cnt >= L2THR) {
                int gb;
                int gsb = cls * NSB + b;
                if (lane == 0) gb = atomicAdd(&subcur[gsb], cnt);
                gb = __shfl(gb, 0);
                uint32* dst = subpairs + (size_t)gsb * SUBCAP;
                for (int k = lane; k < cnt; k += 64)
                    if (gb + k < SUBCAP) dst[gb + k] = sbin[b][k];
                if (lane == 0) scnt[b] = 0;
            }
        }
        __syncthreads();
    }
    for (int b = wv; b < NSB; b += 4) {   // final flush
        int cnt = scnt[b];
        if (cnt > 0) {
            int gb;
            int gsb = cls * NSB + b;
            if (lane == 0) gb = atomicAdd(&subcur[gsb], cnt);
            gb = __shfl(gb, 0);
            uint32* dst = subpairs + (size_t)gsb * SUBCAP;
            for (int k = lane; k < cnt; k += 64)
                if (gb + k < SUBCAP) dst[gb + k] = sbin[b][k];
        }
    }
}

// ---- gather + fused epilogue ---------------------------------------------
// one block per gather-bin (256 blocks = 1/CU), 512 threads.
// Phase B: LDS f32 accumulate (ds_add_f32), 8-deep ILP, coalesced 128B rows.
// Phase C: per-wave MFMA epilogue, weights preloaded in registers,
//          dinv[c] folded into A-frag build, masked stores for tail bin.
__global__ __launch_bounds__(512) void gather_epi_kernel(
    const unsigned short* __restrict__ xb,
    const uint32* __restrict__ subpairs, const int* __restrict__ subcur,
    const float* __restrict__ dinv,
    const float* __restrict__ Wg, const float* __restrict__ bg,
    const float* __restrict__ Wl, const float* __restrict__ bl,
    float* __restrict__ out)
{
    extern __shared__ float facc[];                       // [GW][65] f32
    __shared__ __align__(16) unsigned short hbuf[8][16][72];

    const int gsb = blockIdx.x;
    const int cls = gsb >> 5;
    const int sb = gsb & 31;
    const int lo = cls * DST_PER_CLS + sb * GW;
    int w = DST_PER_CLS - sb * GW; if (w > GW) w = GW;    // 400 or 100

    for (int i = threadIdx.x; i < GW * 65; i += 512) facc[i] = 0.0f;
    __syncthreads();

    const int lane = threadIdx.x & 63;
    const int wv = threadIdx.x >> 6;

    // ---- Phase B: edge accumulation ----
    int cnt = subcur[gsb]; if (cnt > SUBCAP) cnt = SUBCAP;
    const uint32* sp = subpairs + (size_t)gsb * SUBCAP;
    for (int b0 = wv * 64; b0 < cnt; b0 += 512) {
        int take = cnt - b0; if (take > 64) take = 64;
        uint32 p = (lane < take) ? sp[b0 + lane] : 0u;
        int i = 0;
        for (; i + 8 <= take; i += 8) {
            uint32 q0 = __shfl(p, i + 0), q1 = __shfl(p, i + 1);
            uint32 q2 = __shfl(p, i + 2), q3 = __shfl(p, i + 3);
            uint32 q4 = __shfl(p, i + 4), q5 = __shfl(p, i + 5);
            uint32 q6 = __shfl(p, i + 6), q7 = __shfl(p, i + 7);
            float v0 = bf2f(xb[(size_t)(q0 >> 9) * D_IN + lane]);
            float v1 = bf2f(xb[(size_t)(q1 >> 9) * D_IN + lane]);
            float v2 = bf2f(xb[(size_t)(q2 >> 9) * D_IN + lane]);
            float v3 = bf2f(xb[(size_t)(q3 >> 9) * D_IN + lane]);
            float v4 = bf2f(xb[(size_t)(q4 >> 9) * D_IN + lane]);
            float v5 = bf2f(xb[(size_t)(q5 >> 9) * D_IN + lane]);
            float v6 = bf2f(xb[(size_t)(q6 >> 9) * D_IN + lane]);
            float v7 = bf2f(xb[(size_t)(q7 >> 9) * D_IN + lane]);
            atomicAdd(&facc[(q0 & 511u) * 65 + lane], v0);
            atomicAdd(&facc[(q1 & 511u) * 65 + lane], v1);
            atomicAdd(&facc[(q2 & 511u) * 65 + lane], v2);
            atomicAdd(&facc[(q3 & 511u) * 65 + lane], v3);
            atomicAdd(&facc[(q4 & 511u) * 65 + lane], v4);
            atomicAdd(&facc[(q5 & 511u) * 65 + lane], v5);
            atomicAdd(&facc[(q6 & 511u) * 65 + lane], v6);
            atomicAdd(&facc[(q7 & 511u) * 65 + lane], v7);
        }
        for (; i < take; ++i) {
            uint32 q = __shfl(p, i);
            float v = bf2f(xb[(size_t)(q >> 9) * D_IN + lane]);
            atomicAdd(&facc[(q & 511u) * 65 + lane], v);
        }
    }
    __syncthreads();

    // ---- Phase C: fused epilogue ----
    const int lm = lane & 15, lg = lane >> 4, kseg = lg * 8;

    bfx8 wg0[4], wg1[4], wl0[2], wl1[2];
    #pragma unroll
    for (int n = 0; n < 4; ++n) {
        #pragma unroll
        for (int jj = 0; jj < 8; ++jj) {
            wg0[n][jj] = (short)f2bf(Wg[(kseg + jj) * HCH + n * 16 + lm]);
            wg1[n][jj] = (short)f2bf(Wg[(32 + kseg + jj) * HCH + n * 16 + lm]);
        }
    }
    #pragma unroll
    for (int n = 0; n < 2; ++n) {
        #pragma unroll
        for (int jj = 0; jj < 8; ++jj) {
            wl0[n][jj] = (short)f2bf(Wl[(kseg + jj) * D_OUT + n * 16 + lm]);
            wl1[n][jj] = (short)f2bf(Wl[(32 + kseg + jj) * D_OUT + n * 16 + lm]);
        }
    }
    float bgv[4], blv[2];
    #pragma unroll
    for (int n = 0; n < 4; ++n) bgv[n] = bg[n * 16 + lm];
    #pragma unroll
    for (int n = 0; n < 2; ++n) blv[n] = bl[n * 16 + lm];

    const int ntile = (w + 15) >> 4;
    for (int t = wv; t < ntile; t += 8) {
        const int m0 = t * 16;
        const int arow = m0 + lm;
        const int didx = (arow < w) ? arow : (w - 1);
        const float dv = dinv[lo + didx];
        const float* fr = &facc[arow * 65];

        bfx8 a0, a1;
        #pragma unroll
        for (int jj = 0; jj < 8; ++jj) {
            a0[jj] = (short)f2bf(fr[kseg + jj] * dv);
            a1[jj] = (short)f2bf(fr[32 + kseg + jj] * dv);
        }

        #pragma unroll
        for (int n = 0; n < 4; ++n) {
            f32x4 cacc = {0.0f, 0.0f, 0.0f, 0.0f};
            cacc = __builtin_amdgcn_mfma_f32_16x16x32_bf16(a0, wg0[n], cacc, 0, 0, 0);
            cacc = __builtin_amdgcn_mfma_f32_16x16x32_bf16(a1, wg1[n], cacc, 0, 0, 0);
            #pragma unroll
            for (int i = 0; i < 4; ++i) {
                float h = fmaxf(cacc[i] + bgv[n], 0.0f);
                hbuf[wv][lg * 4 + i][n * 16 + lm] = f2bf(h);
            }
        }
        // per-wave hbuf: same-wave RAW, compiler inserts lgkmcnt waits
        bfx8 a20 = *(const bfx8*)(&hbuf[wv][lm][kseg]);
        bfx8 a21 = *(const bfx8*)(&hbuf[wv][lm][32 + kseg]);

        #pragma unroll
        for (int n2 = 0; n2 < 2; ++n2) {
            f32x4 d = {0.0f, 0.0f, 0.0f, 0.0f};
            d = __builtin_amdgcn_mfma_f32_16x16x32_bf16(a20, wl0[n2], d, 0, 0, 0);
            d = __builtin_amdgcn_mfma_f32_16x16x32_bf16(a21, wl1[n2], d, 0, 0, 0);
            #pragma unroll
            for (int i = 0; i < 4; ++i) {
                int mrow = m0 + lg * 4 + i;
                if (mrow < w)
                    out[(size_t)(lo + mrow) * D_OUT + n2 * 16 + lm] = d[i] + blv[n2];
            }
        }
    }
}

extern "C" void kernel_launch(void* const* d_in, const int* in_sizes, int n_in,
                              void* d_out, int out_size, void* d_ws, size_t ws_size,
                              hipStream_t stream) {
    const float* x_local = (const float*)d_in[0];
    const float* W_gcn   = (const float*)d_in[2];
    const float* b_gcn   = (const float*)d_in[3];
    const float* W_lin   = (const float*)d_in[10];
    const float* b_lin   = (const float*)d_in[11];
    const int*   edge_ll = (const int*)d_in[12];
    const int*   row = edge_ll;           // edge_ll[0, :]
    const int*   col = edge_ll + E_LL;    // edge_ll[1, :]

    // workspace layout (~22.5 MB)
    char* base = (char*)d_ws;
    int*    deg_i      = (int*)(base + 0);            // 400000 B
    int*    classcur   = (int*)(base + 400000);       // 32 B
    int*    subcur     = (int*)(base + 400032);       // 1024 B
    float*  dinvp      = (float*)(base + 401408);     // 400000 B
    uint32* classpairs = (uint32*)(base + 801536);    // 4,194,304 B
    uint32* subpairs   = (uint32*)(base + 4996096);   // 4,718,592 B
    unsigned short* xb = (unsigned short*)(base + 9714944);  // 12,800,000 B
    float* out = (float*)d_out;

    // zero deg + classcur + subcur in one shot
    (void)hipMemsetAsync(base, 0, 401056, stream);

    binclass_kernel<<<512, 256, 0, stream>>>(row, col, deg_i, classcur, classpairs);
    dinv_kernel<<<(N_L + 255) / 256, 256, 0, stream>>>(deg_i, dinvp, N_L);
    xbconv_kernel<<<2048, 256, 0, stream>>>(x_local, dinvp, xb);
    binsub_kernel<<<NCLS * BINSUB_BPC, 256, 0, stream>>>(
        classcur, classpairs, subcur, subpairs);
    gather_epi_kernel<<<NGSB, 512, GW * 65 * sizeof(float), stream>>>(
        xb, subpairs, subcur, dinvp, W_gcn, b_gcn, W_lin, b_lin, out);
}

// Round 10
// 523.787 us; speedup vs baseline: 1.0035x; 1.0035x over previous
//
#include <hip/hip_runtime.h>

#define N_L 100000
#define N_V 1000
#define D_IN 64
#define HCH 64
#define D_OUT 32
#define E_LL 1000000

#define NCLS 8
#define DST_PER_CLS 12500        // N_L / 8
#define CLSCAP 131072            // class list capacity (mean 125000, +18 sigma)
#define GW 400                   // gather-bin node width
#define NSB 32                   // gather bins per class (31*400 + 100 = 12500)
#define NGSB 256                 // total gather bins = 1 block per CU
#define SUBCAP 4608              // per-bin pair capacity (mean 4000, +9.6 sigma)

#define L1CAP 768                // 8 class bins: no-reject (511 + 256 <= 767)
#define L1THR 512
#define L2CAP 384                // 32 sub bins: no-reject (127 + 256 <= 383)
#define L2THR 128
#define BINSUB_BPC 15            // binsub blocks per class

typedef unsigned int uint32;
typedef __attribute__((ext_vector_type(8))) short bfx8;    // 8 bf16 (4 VGPR)
typedef __attribute__((ext_vector_type(4))) float f32x4;   // MFMA C/D frag
typedef __attribute__((ext_vector_type(4))) float fvec4;
typedef __attribute__((ext_vector_type(4))) unsigned short usvec4;

__device__ inline float bf2f(unsigned short u) {
    return __uint_as_float(((uint32)u) << 16);
}
__device__ inline unsigned short f2bf(float f) {   // round-to-nearest-even
    uint32 u = __float_as_uint(f);
    u = (u + 0x7fffu + ((u >> 16) & 1u)) >> 16;
    return (unsigned short)u;
}

// ---- level-1: single edge scan; fused deg atomics; class-binned COO ------
// pack = (r << 14) | (c - cls*12500)   [r:17b, c_lo:14b]
__global__ __launch_bounds__(256) void binclass_kernel(
    const int* __restrict__ row, const int* __restrict__ col,
    int* __restrict__ deg, int* __restrict__ classcur,
    uint32* __restrict__ classpairs)
{
    __shared__ uint32 sbin[NCLS][L1CAP];
    __shared__ int scnt[NCLS];
    if (threadIdx.x < NCLS) scnt[threadIdx.x] = 0;
    __syncthreads();

    const int per = (E_LL + gridDim.x - 1) / gridDim.x;
    const int beg = blockIdx.x * per;
    const int end = (beg + per < E_LL) ? beg + per : E_LL;
    const int lane = threadIdx.x & 63;
    const int wv = threadIdx.x >> 6;

    for (int i0 = beg; i0 < end; i0 += 256) {
        int i = i0 + threadIdx.x;
        if (i < end) {
            int c = col[i];
            int r = row[i];
            atomicAdd(&deg[c], 1);
            int cls = c / DST_PER_CLS;
            uint32 pack = ((uint32)r << 14) | (uint32)(c - cls * DST_PER_CLS);
            int slot = atomicAdd(&scnt[cls], 1);   // < L1CAP guaranteed
            sbin[cls][slot] = pack;
        }
        __syncthreads();
        for (int b = wv; b < NCLS; b += 4) {
            int cnt = scnt[b];
            if (cnt >= L1THR) {
                int gb;
                if (lane == 0) gb = atomicAdd(&classcur[b], cnt);
                gb = __shfl(gb, 0);
                uint32* dst = classpairs + (size_t)b * CLSCAP;
                for (int k = lane; k < cnt; k += 64)
                    if (gb + k < CLSCAP) dst[gb + k] = sbin[b][k];
                if (lane == 0) scnt[b] = 0;
            }
        }
        __syncthreads();
    }
    for (int b = wv; b < NCLS; b += 4) {   // final flush
        int cnt = scnt[b];
        if (cnt > 0) {
            int gb;
            if (lane == 0) gb = atomicAdd(&classcur[b], cnt);
            gb = __shfl(gb, 0);
            uint32* dst = classpairs + (size_t)b * CLSCAP;
            for (int k = lane; k < cnt; k += 64)
                if (gb + k < CLSCAP) dst[gb + k] = sbin[b][k];
        }
    }
}

// ---- dinv[i] = deg>0 ? rsqrt(deg) : 0 ------------------------------------
__global__ void dinv_kernel(const int* __restrict__ deg,
                            float* __restrict__ dinv, int n) {
    int i = blockIdx.x * blockDim.x + threadIdx.x;
    if (i < n) {
        int d = deg[i];
        dinv[i] = (d > 0) ? rsqrtf((float)d) : 0.0f;
    }
}

// ---- xb[r,:] = bf16(x[r,:] * dinv[r]) ------------------------------------
__global__ void xbconv_kernel(const float* __restrict__ x,
                              const float* __restrict__ dinv,
                              unsigned short* __restrict__ xb) {
    int n4 = N_L * D_IN / 4;
    int idx = blockIdx.x * blockDim.x + threadIdx.x;
    int stride = gridDim.x * blockDim.x;
    for (; idx < n4; idx += stride) {
        fvec4 v = ((const fvec4*)x)[idx];
        float d = dinv[idx >> 4];
        usvec4 o;
        o.x = f2bf(v.x * d);
        o.y = f2bf(v.y * d);
        o.z = f2bf(v.z * d);
        o.w = f2bf(v.w * d);
        ((usvec4*)xb)[idx] = o;
    }
}

// ---- level-2: class COO -> 32 gather-bins per class ----------------------
// pack2 = (r << 9) | (c_lo - sb*400)   [r:17b, c_in_bin:9b]
__global__ __launch_bounds__(256) void binsub_kernel(
    const int* __restrict__ classcur, const uint32* __restrict__ classpairs,
    int* __restrict__ subcur, uint32* __restrict__ subpairs)
{
    __shared__ uint32 sbin[NSB][L2CAP];
    __shared__ int scnt[NSB];
    if (threadIdx.x < NSB) scnt[threadIdx.x] = 0;
    __syncthreads();

    const int cls = blockIdx.x / BINSUB_BPC;
    const int chunk = blockIdx.x % BINSUB_BPC;
    int len = classcur[cls]; if (len > CLSCAP) len = CLSCAP;
    const int beg = (int)((long long)len * chunk / BINSUB_BPC);
    const int end = (int)((long long)len * (chunk + 1) / BINSUB_BPC);
    const uint32* cp = classpairs + (size_t)cls * CLSCAP;
    const int lane = threadIdx.x & 63;
    const int wv = threadIdx.x >> 6;

    for (int i0 = beg; i0 < end; i0 += 256) {
        int i = i0 + threadIdx.x;
        if (i < end) {
            uint32 p = cp[i];
            int c_lo = (int)(p & 16383u);
            uint32 r = p >> 14;
            int sb = c_lo / GW;
            uint32 pack = (r << 9) | (uint32)(c_lo - sb * GW);
            int slot = atomicAdd(&scnt[sb], 1);    // < L2CAP guaranteed
            sbin[sb][slot] = pack;
        }
        __syncthreads();
        for (int b = wv; b < NSB; b += 4) {
            int cnt = scnt[b];
            if (cnt >= L2THR) {
                int gb;
                int gsb = cls * NSB + b;
                if (lane == 0) gb = atomicAdd(&subcur[gsb], cnt);
                gb = __shfl(gb, 0);
                uint32* dst = subpairs + (size_t)gsb * SUBCAP;
                for (int k = lane; k < cnt; k += 64)
                    if (gb + k < SUBCAP) dst[gb + k] = sbin[b][k];
                if (lane == 0) scnt[b] = 0;
            }
        }
        __syncthreads();
    }
    for (int b = wv; b < NSB; b += 4) {   // final flush
        int cnt = scnt[b];
        if (cnt > 0) {
            int gb;
            int gsb = cls * NSB + b;
            if (lane == 0) gb = atomicAdd(&subcur[gsb], cnt);
            gb = __shfl(gb, 0);
            uint32* dst = subpairs + (size_t)gsb * SUBCAP;
            for (int k = lane; k < cnt; k += 64)
                if (gb + k < SUBCAP) dst[gb + k] = sbin[b][k];
        }
    }
}

// ---- gather + fused epilogue ---------------------------------------------
// one block per gather-bin, 1024 threads (16 waves = 4/SIMD: 2x TLP vs r9).
// Phase B: LDS f32 accumulate, ILP-16 (16 xb-row loads in flight per wave).
// Phase C: per-wave MFMA epilogue, weights preloaded in registers.
__global__ __launch_bounds__(1024) void gather_epi_kernel(
    const unsigned short* __restrict__ xb,
    const uint32* __restrict__ subpairs, const int* __restrict__ subcur,
    const float* __restrict__ dinv,
    const float* __restrict__ Wg, const float* __restrict__ bg,
    const float* __restrict__ Wl, const float* __restrict__ bl,
    float* __restrict__ out)
{
    extern __shared__ float facc[];                       // [GW][65] f32
    __shared__ __align__(16) unsigned short hbuf[16][16][72];

    const int gsb = blockIdx.x;
    const int cls = gsb >> 5;
    const int sb = gsb & 31;
    const int lo = cls * DST_PER_CLS + sb * GW;
    int w = DST_PER_CLS - sb * GW; if (w > GW) w = GW;    // 400 or 100

    for (int i = threadIdx.x; i < GW * 65; i += 1024) facc[i] = 0.0f;
    __syncthreads();

    const int lane = threadIdx.x & 63;
    const int wv = threadIdx.x >> 6;

    // ---- Phase B: edge accumulation, ILP-16 ----
    int cnt = subcur[gsb]; if (cnt > SUBCAP) cnt = SUBCAP;
    const uint32* sp = subpairs + (size_t)gsb * SUBCAP;
    for (int b0 = wv * 64; b0 < cnt; b0 += 1024) {
        int take = cnt - b0; if (take > 64) take = 64;
        uint32 p = (lane < take) ? sp[b0 + lane] : 0u;
        int i = 0;
        for (; i + 16 <= take; i += 16) {
            uint32 q[16];
            float v[16];
            #pragma unroll
            for (int k = 0; k < 16; ++k) q[k] = __shfl(p, i + k);
            #pragma unroll
            for (int k = 0; k < 16; ++k)
                v[k] = bf2f(xb[(size_t)(q[k] >> 9) * D_IN + lane]);
            #pragma unroll
            for (int k = 0; k < 16; ++k)
                atomicAdd(&facc[(q[k] & 511u) * 65 + lane], v[k]);
        }
        for (; i < take; ++i) {
            uint32 q = __shfl(p, i);
            float v = bf2f(xb[(size_t)(q >> 9) * D_IN + lane]);
            atomicAdd(&facc[(q & 511u) * 65 + lane], v);
        }
    }
    __syncthreads();

    // ---- Phase C: fused epilogue ----
    const int lm = lane & 15, lg = lane >> 4, kseg = lg * 8;

    bfx8 wg0[4], wg1[4], wl0[2], wl1[2];
    #pragma unroll
    for (int n = 0; n < 4; ++n) {
        #pragma unroll
        for (int jj = 0; jj < 8; ++jj) {
            wg0[n][jj] = (short)f2bf(Wg[(kseg + jj) * HCH + n * 16 + lm]);
            wg1[n][jj] = (short)f2bf(Wg[(32 + kseg + jj) * HCH + n * 16 + lm]);
        }
    }
    #pragma unroll
    for (int n = 0; n < 2; ++n) {
        #pragma unroll
        for (int jj = 0; jj < 8; ++jj) {
            wl0[n][jj] = (short)f2bf(Wl[(kseg + jj) * D_OUT + n * 16 + lm]);
            wl1[n][jj] = (short)f2bf(Wl[(32 + kseg + jj) * D_OUT + n * 16 + lm]);
        }
    }
    float bgv[4], blv[2];
    #pragma unroll
    for (int n = 0; n < 4; ++n) bgv[n] = bg[n * 16 + lm];
    #pragma unroll
    for (int n = 0; n < 2; ++n) blv[n] = bl[n * 16 + lm];

    const int ntile = (w + 15) >> 4;
    for (int t = wv; t < ntile; t += 16) {
        const int m0 = t * 16;
        const int arow = m0 + lm;
        const int didx = (arow < w) ? arow : (w - 1);
        const float dv = dinv[lo + didx];
        const float* fr = &facc[arow * 65];

        bfx8 a0, a1;
        #pragma unroll
        for (int jj = 0; jj < 8; ++jj) {
            a0[jj] = (short)f2bf(fr[kseg + jj] * dv);
            a1[jj] = (short)f2bf(fr[32 + kseg + jj] * dv);
        }

        #pragma unroll
        for (int n = 0; n < 4; ++n) {
            f32x4 cacc = {0.0f, 0.0f, 0.0f, 0.0f};
            cacc = __builtin_amdgcn_mfma_f32_16x16x32_bf16(a0, wg0[n], cacc, 0, 0, 0);
            cacc = __builtin_amdgcn_mfma_f32_16x16x32_bf16(a1, wg1[n], cacc, 0, 0, 0);
            #pragma unroll
            for (int i = 0; i < 4; ++i) {
                float h = fmaxf(cacc[i] + bgv[n], 0.0f);
                hbuf[wv][lg * 4 + i][n * 16 + lm] = f2bf(h);
            }
        }
        // per-wave hbuf: same-wave RAW, compiler inserts lgkmcnt waits
        bfx8 a20 = *(const bfx8*)(&hbuf[wv][lm][kseg]);
        bfx8 a21 = *(const bfx8*)(&hbuf[wv][lm][32 + kseg]);

        #pragma unroll
        for (int n2 = 0; n2 < 2; ++n2) {
            f32x4 d = {0.0f, 0.0f, 0.0f, 0.0f};
            d = __builtin_amdgcn_mfma_f32_16x16x32_bf16(a20, wl0[n2], d, 0, 0, 0);
            d = __builtin_amdgcn_mfma_f32_16x16x32_bf16(a21, wl1[n2], d, 0, 0, 0);
            #pragma unroll
            for (int i = 0; i < 4; ++i) {
                int mrow = m0 + lg * 4 + i;
                if (mrow < w)
                    out[(size_t)(lo + mrow) * D_OUT + n2 * 16 + lm] = d[i] + blv[n2];
            }
        }
    }
}

extern "C" void kernel_launch(void* const* d_in, const int* in_sizes, int n_in,
                              void* d_out, int out_size, void* d_ws, size_t ws_size,
                              hipStream_t stream) {
    const float* x_local = (const float*)d_in[0];
    const float* W_gcn   = (const float*)d_in[2];
    const float* b_gcn   = (const float*)d_in[3];
    const float* W_lin   = (const float*)d_in[10];
    const float* b_lin   = (const float*)d_in[11];
    const int*   edge_ll = (const int*)d_in[12];
    const int*   row = edge_ll;           // edge_ll[0, :]
    const int*   col = edge_ll + E_LL;    // edge_ll[1, :]

    // workspace layout (~22.5 MB)
    char* base = (char*)d_ws;
    int*    deg_i      = (int*)(base + 0);            // 400000 B
    int*    classcur   = (int*)(base + 400000);       // 32 B
    int*    subcur     = (int*)(base + 400032);       // 1024 B
    float*  dinvp      = (float*)(base + 401408);     // 400000 B
    uint32* classpairs = (uint32*)(base + 801536);    // 4,194,304 B
    uint32* subpairs   = (uint32*)(base + 4996096);   // 4,718,592 B
    unsigned short* xb = (unsigned short*)(base + 9714944);  // 12,800,000 B
    float* out = (float*)d_out;

    // zero deg + classcur + subcur in one shot
    (void)hipMemsetAsync(base, 0, 401056, stream);

    binclass_kernel<<<512, 256, 0, stream>>>(row, col, deg_i, classcur, classpairs);
    dinv_kernel<<<(N_L + 255) / 256, 256, 0, stream>>>(deg_i, dinvp, N_L);
    xbconv_kernel<<<2048, 256, 0, stream>>>(x_local, dinvp, xb);
    binsub_kernel<<<NCLS * BINSUB_BPC, 256, 0, stream>>>(
        classcur, classpairs, subcur, subpairs);
    gather_epi_kernel<<<NGSB, 1024, GW * 65 * sizeof(float), stream>>>(
        xb, subpairs, subcur, dinvp, W_gcn, b_gcn, W_lin, b_lin, out);
}

// Round 11
// 221.654 us; speedup vs baseline: 2.3713x; 2.3631x over previous
//
#include <hip/hip_runtime.h>

#define N_L 100000
#define N_V 1000
#define D_IN 64
#define HCH 64
#define D_OUT 32
#define E_LL 1000000

#define NCLS 8
#define DST_PER_CLS 12500        // N_L / 8
#define CLSCAP 131072            // class list capacity
#define GW 400                   // gather-bin node width
#define NSB 32                   // gather bins per class
#define NGSB 256                 // total gather bins = 1 block per CU
#define SUBCAP 4608              // per-bin pair capacity (mean 3906, +11 sigma)

#define L1CAP 768                // no-reject: 511 + 256 <= 767
#define L1THR 512
#define L2CAP 384                // no-reject: 127 + 256 <= 383
#define L2THR 128
#define BINSUB_BPC 15            // binsub blocks per class

typedef unsigned int uint32;
typedef unsigned long long u64;
typedef __attribute__((ext_vector_type(8))) short bfx8;    // 8 bf16 (4 VGPR)
typedef __attribute__((ext_vector_type(4))) float f32x4;   // MFMA C/D frag
typedef __attribute__((ext_vector_type(4))) float fvec4;
typedef __attribute__((ext_vector_type(4))) unsigned short usvec4;

__device__ inline float bf2f(unsigned short u) {
    return __uint_as_float(((uint32)u) << 16);
}
__device__ inline unsigned short f2bf(float f) {   // round-to-nearest-even
    uint32 u = __float_as_uint(f);
    u = (u + 0x7fffu + ((u >> 16) & 1u)) >> 16;
    return (unsigned short)u;
}

// ---- level-1: edge scan; fused deg atomics; class-binned COO -------------
// pack = (r << 14) | (c - cls*12500).  Wave-aggregated slot allocation:
// ballot per cls bit -> group mask -> leader does ONE scnt atomic per class.
__global__ __launch_bounds__(256) void binclass_kernel(
    const int* __restrict__ row, const int* __restrict__ col,
    int* __restrict__ deg, int* __restrict__ classcur,
    uint32* __restrict__ classpairs)
{
    __shared__ uint32 sbin[NCLS][L1CAP];
    __shared__ int scnt[NCLS];
    if (threadIdx.x < NCLS) scnt[threadIdx.x] = 0;
    __syncthreads();

    const int per = (E_LL + gridDim.x - 1) / gridDim.x;
    const int beg = blockIdx.x * per;
    const int end = (beg + per < E_LL) ? beg + per : E_LL;
    const int lane = threadIdx.x & 63;
    const int wv = threadIdx.x >> 6;

    for (int i0 = beg; i0 < end; i0 += 256) {
        int i = i0 + threadIdx.x;
        if (i < end) {
            int c = col[i];
            int r = row[i];
            atomicAdd(&deg[c], 1);
            int cls = c / DST_PER_CLS;
            uint32 pack = ((uint32)r << 14) | (uint32)(c - cls * DST_PER_CLS);
            u64 act = __ballot(1);
            u64 b0 = __ballot(cls & 1);
            u64 b1 = __ballot(cls & 2);
            u64 b2 = __ballot(cls & 4);
            u64 mask = ((cls & 1) ? b0 : ~b0) & ((cls & 2) ? b1 : ~b1)
                     & ((cls & 4) ? b2 : ~b2) & act;
            int leader = __ffsll(mask) - 1;
            int rank = __popcll(mask & ((1ull << lane) - 1ull));
            int base = 0;
            if (lane == leader) base = atomicAdd(&scnt[cls], __popcll(mask));
            base = __shfl(base, leader);
            sbin[cls][base + rank] = pack;
        }
        __syncthreads();
        for (int b = wv; b < NCLS; b += 4) {
            int cnt = scnt[b];
            if (cnt >= L1THR) {
                int gb;
                if (lane == 0) gb = atomicAdd(&classcur[b], cnt);
                gb = __shfl(gb, 0);
                uint32* dst = classpairs + (size_t)b * CLSCAP;
                for (int k = lane; k < cnt; k += 64)
                    if (gb + k < CLSCAP) dst[gb + k] = sbin[b][k];
                if (lane == 0) scnt[b] = 0;
            }
        }
        __syncthreads();
    }
    for (int b = wv; b < NCLS; b += 4) {   // final flush
        int cnt = scnt[b];
        if (cnt > 0) {
            int gb;
            if (lane == 0) gb = atomicAdd(&classcur[b], cnt);
            gb = __shfl(gb, 0);
            uint32* dst = classpairs + (size_t)b * CLSCAP;
            for (int k = lane; k < cnt; k += 64)
                if (gb + k < CLSCAP) dst[gb + k] = sbin[b][k];
        }
    }
}

// ---- dinv[i] = deg>0 ? rsqrt(deg) : 0 ------------------------------------
__global__ void dinv_kernel(const int* __restrict__ deg,
                            float* __restrict__ dinv, int n) {
    int i = blockIdx.x * blockDim.x + threadIdx.x;
    if (i < n) {
        int d = deg[i];
        dinv[i] = (d > 0) ? rsqrtf((float)d) : 0.0f;
    }
}

// ---- xb[r,:] = bf16(x[r,:] * dinv[r]) ------------------------------------
__global__ void xbconv_kernel(const float* __restrict__ x,
                              const float* __restrict__ dinv,
                              unsigned short* __restrict__ xb) {
    int n4 = N_L * D_IN / 4;
    int idx = blockIdx.x * blockDim.x + threadIdx.x;
    int stride = gridDim.x * blockDim.x;
    for (; idx < n4; idx += stride) {
        fvec4 v = ((const fvec4*)x)[idx];
        float d = dinv[idx >> 4];
        usvec4 o;
        o.x = f2bf(v.x * d);
        o.y = f2bf(v.y * d);
        o.z = f2bf(v.z * d);
        o.w = f2bf(v.w * d);
        ((usvec4*)xb)[idx] = o;
    }
}

// ---- level-2: class COO -> 32 gather-bins per class (wave-aggregated) ----
// pack2 = (r << 9) | (c_lo - sb*400)
__global__ __launch_bounds__(256) void binsub_kernel(
    const int* __restrict__ classcur, const uint32* __restrict__ classpairs,
    int* __restrict__ subcur, uint32* __restrict__ subpairs)
{
    __shared__ uint32 sbin[NSB][L2CAP];
    __shared__ int scnt[NSB];
    if (threadIdx.x < NSB) scnt[threadIdx.x] = 0;
    __syncthreads();

    const int cls = blockIdx.x / BINSUB_BPC;
    const int chunk = blockIdx.x % BINSUB_BPC;
    int len = classcur[cls]; if (len > CLSCAP) len = CLSCAP;
    const int beg = (int)((long long)len * chunk / BINSUB_BPC);
    const int end = (int)((long long)len * (chunk + 1) / BINSUB_BPC);
    const uint32* cp = classpairs + (size_t)cls * CLSCAP;
    const int lane = threadIdx.x & 63;
    const int wv = threadIdx.x >> 6;

    for (int i0 = beg; i0 < end; i0 += 256) {
        int i = i0 + threadIdx.x;
        if (i < end) {
            uint32 p = cp[i];
            int c_lo = (int)(p & 16383u);
            uint32 r = p >> 14;
            int sb = c_lo / GW;
            uint32 pack = (r << 9) | (uint32)(c_lo - sb * GW);
            u64 act = __ballot(1);
            u64 b0 = __ballot(sb & 1);
            u64 b1 = __ballot(sb & 2);
            u64 b2 = __ballot(sb & 4);
            u64 b3 = __ballot(sb & 8);
            u64 b4 = __ballot(sb & 16);
            u64 mask = ((sb & 1) ? b0 : ~b0) & ((sb & 2) ? b1 : ~b1)
                     & ((sb & 4) ? b2 : ~b2) & ((sb & 8) ? b3 : ~b3)
                     & ((sb & 16) ? b4 : ~b4) & act;
            int leader = __ffsll(mask) - 1;
            int rank = __popcll(mask & ((1ull << lane) - 1ull));
            int base = 0;
            if (lane == leader) base = atomicAdd(&scnt[sb], __popcll(mask));
            base = __shfl(base, leader);
            sbin[sb][base + rank] = pack;
        }
        __syncthreads();
        for (int b = wv; b < NSB; b += 4) {
            int cnt = scnt[b];
            if (cnt >= L2THR) {
                int gb;
                int gsb = cls * NSB + b;
                if (lane == 0) gb = atomicAdd(&subcur[gsb], cnt);
                gb = __shfl(gb, 0);
                uint32* dst = subpairs + (size_t)gsb * SUBCAP;
                for (int k = lane; k < cnt; k += 64)
                    if (gb + k < SUBCAP) dst[gb + k] = sbin[b][k];
                if (lane == 0) scnt[b] = 0;
            }
        }
        __syncthreads();
    }
    for (int b = wv; b < NSB; b += 4) {   // final flush
        int cnt = scnt[b];
        if (cnt > 0) {
            int gb;
            int gsb = cls * NSB + b;
            if (lane == 0) gb = atomicAdd(&subcur[gsb], cnt);
            gb = __shfl(gb, 0);
            uint32* dst = subpairs + (size_t)gsb * SUBCAP;
            for (int k = lane; k < cnt; k += 64)
                if (gb + k < SUBCAP) dst[gb + k] = sbin[b][k];
        }
    }
}

// ---- gather + fused epilogue: NO per-edge LDS atomics --------------------
// Per bin: (1) count per-node (lane=edge: 64 edges/atomic-instr),
// (2) LDS scan -> rowptr, (3) place r's into sorted per-node lists,
// (4) per-node REGISTER accumulation (broadcast LDS read + coalesced xb row),
// one bf16 ds_write per node into hacc, (5) MFMA epilogue from hacc.
__global__ __launch_bounds__(1024) void gather_epi_kernel(
    const unsigned short* __restrict__ xb,
    const uint32* __restrict__ subpairs, const int* __restrict__ subcur,
    const float* __restrict__ dinv,
    const float* __restrict__ Wg, const float* __restrict__ bg,
    const float* __restrict__ Wl, const float* __restrict__ bl,
    float* __restrict__ out)
{
    extern __shared__ char smem[];
    unsigned short* hacc = (unsigned short*)smem;              // [400][72] bf16
    unsigned short* hbufp = (unsigned short*)(smem + 57600);   // [16][16][72]
    uint32* sorted = (uint32*)(smem + 94464);                  // [SUBCAP]
    int* rptr  = (int*)(smem + 112896);                        // [512] counts->excl scan
    int* scan2 = (int*)(smem + 114944);                        // [512]
    int* cur   = (int*)(smem + 116992);                        // [400]

    const int gsb = blockIdx.x;
    const int cls = gsb >> 5;
    const int sb = gsb & 31;
    const int lo = cls * DST_PER_CLS + sb * GW;
    int w = DST_PER_CLS - sb * GW; if (w > GW) w = GW;    // 400 or 100

    const int tid = threadIdx.x;
    const int lane = tid & 63;
    const int wv = tid >> 6;

    int cnt = subcur[gsb]; if (cnt > SUBCAP) cnt = SUBCAP;
    const uint32* sp = subpairs + (size_t)gsb * SUBCAP;

    // (1) count
    if (tid < 512) rptr[tid] = 0;
    __syncthreads();
    for (int i = tid; i < cnt; i += 1024)
        atomicAdd(&rptr[sp[i] & 511u], 1);
    __syncthreads();

    // (2) exclusive scan over 512 (Hillis-Steele)
    int v = (tid < 512) ? rptr[tid] : 0;
    if (tid < 512) scan2[tid] = v;
    __syncthreads();
    for (int ofs = 1; ofs < 512; ofs <<= 1) {
        int add = (tid < 512 && tid >= ofs) ? scan2[tid - ofs] : 0;
        __syncthreads();
        if (tid < 512) scan2[tid] += add;
        __syncthreads();
    }
    if (tid < 512) {
        int ex = scan2[tid] - v;
        rptr[tid] = ex;                 // rptr[c] = start; rptr[400] = cnt
        if (tid < 400) cur[tid] = ex;
    }
    __syncthreads();

    // (3) place (LDS scattered writes + low-contention int atomics)
    for (int i = tid; i < cnt; i += 1024) {
        uint32 p = sp[i];
        int pos = atomicAdd(&cur[p & 511u], 1);
        sorted[pos] = p >> 9;           // r
    }
    __syncthreads();

    // (4) per-node register accumulation
    for (int c = wv; c < w; c += 16) {
        int s = rptr[c], e = rptr[c + 1];
        float a0 = 0.0f, a1 = 0.0f, a2 = 0.0f, a3 = 0.0f;
        int j = s;
        for (; j + 4 <= e; j += 4) {
            int r0 = sorted[j], r1 = sorted[j + 1];
            int r2 = sorted[j + 2], r3 = sorted[j + 3];
            a0 += bf2f(xb[(size_t)r0 * D_IN + lane]);
            a1 += bf2f(xb[(size_t)r1 * D_IN + lane]);
            a2 += bf2f(xb[(size_t)r2 * D_IN + lane]);
            a3 += bf2f(xb[(size_t)r3 * D_IN + lane]);
        }
        for (; j < e; ++j) {
            int r = sorted[j];
            a0 += bf2f(xb[(size_t)r * D_IN + lane]);
        }
        float dv = dinv[lo + c];
        hacc[c * 72 + lane] = f2bf(((a0 + a1) + (a2 + a3)) * dv);
    }
    __syncthreads();

    // (5) MFMA epilogue
    const int lm = lane & 15, lg = lane >> 4, kseg = lg * 8;

    bfx8 wg0[4], wg1[4], wl0[2], wl1[2];
    #pragma unroll
    for (int n = 0; n < 4; ++n) {
        #pragma unroll
        for (int jj = 0; jj < 8; ++jj) {
            wg0[n][jj] = (short)f2bf(Wg[(kseg + jj) * HCH + n * 16 + lm]);
            wg1[n][jj] = (short)f2bf(Wg[(32 + kseg + jj) * HCH + n * 16 + lm]);
        }
    }
    #pragma unroll
    for (int n = 0; n < 2; ++n) {
        #pragma unroll
        for (int jj = 0; jj < 8; ++jj) {
            wl0[n][jj] = (short)f2bf(Wl[(kseg + jj) * D_OUT + n * 16 + lm]);
            wl1[n][jj] = (short)f2bf(Wl[(32 + kseg + jj) * D_OUT + n * 16 + lm]);
        }
    }
    float bgv[4], blv[2];
    #pragma unroll
    for (int n = 0; n < 4; ++n) bgv[n] = bg[n * 16 + lm];
    #pragma unroll
    for (int n = 0; n < 2; ++n) blv[n] = bl[n * 16 + lm];

    const int ntile = (w + 15) >> 4;
    for (int t = wv; t < ntile; t += 16) {
        const int m0 = t * 16;
        const int arow = m0 + lm;       // rows >= w read garbage; masked on store
        const unsigned short* fr = hacc + arow * 72;
        bfx8 a0 = *(const bfx8*)(fr + kseg);
        bfx8 a1 = *(const bfx8*)(fr + 32 + kseg);

        unsigned short* hb = hbufp + wv * (16 * 72);
        #pragma unroll
        for (int n = 0; n < 4; ++n) {
            f32x4 cacc = {0.0f, 0.0f, 0.0f, 0.0f};
            cacc = __builtin_amdgcn_mfma_f32_16x16x32_bf16(a0, wg0[n], cacc, 0, 0, 0);
            cacc = __builtin_amdgcn_mfma_f32_16x16x32_bf16(a1, wg1[n], cacc, 0, 0, 0);
            #pragma unroll
            for (int i = 0; i < 4; ++i) {
                float h = fmaxf(cacc[i] + bgv[n], 0.0f);
                hb[(lg * 4 + i) * 72 + n * 16 + lm] = f2bf(h);
            }
        }
        bfx8 a20 = *(const bfx8*)(hb + lm * 72 + kseg);
        bfx8 a21 = *(const bfx8*)(hb + lm * 72 + 32 + kseg);

        #pragma unroll
        for (int n2 = 0; n2 < 2; ++n2) {
            f32x4 d = {0.0f, 0.0f, 0.0f, 0.0f};
            d = __builtin_amdgcn_mfma_f32_16x16x32_bf16(a20, wl0[n2], d, 0, 0, 0);
            d = __builtin_amdgcn_mfma_f32_16x16x32_bf16(a21, wl1[n2], d, 0, 0, 0);
            #pragma unroll
            for (int i = 0; i < 4; ++i) {
                int mrow = m0 + lg * 4 + i;
                if (mrow < w)
                    out[(size_t)(lo + mrow) * D_OUT + n2 * 16 + lm] = d[i] + blv[n2];
            }
        }
    }
}

extern "C" void kernel_launch(void* const* d_in, const int* in_sizes, int n_in,
                              void* d_out, int out_size, void* d_ws, size_t ws_size,
                              hipStream_t stream) {
    const float* x_local = (const float*)d_in[0];
    const float* W_gcn   = (const float*)d_in[2];
    const float* b_gcn   = (const float*)d_in[3];
    const float* W_lin   = (const float*)d_in[10];
    const float* b_lin   = (const float*)d_in[11];
    const int*   edge_ll = (const int*)d_in[12];
    const int*   row = edge_ll;           // edge_ll[0, :]
    const int*   col = edge_ll + E_LL;    // edge_ll[1, :]

    // workspace layout (~22.5 MB)
    char* base = (char*)d_ws;
    int*    deg_i      = (int*)(base + 0);            // 400000 B
    int*    classcur   = (int*)(base + 400000);       // 32 B
    int*    subcur     = (int*)(base + 400032);       // 1024 B
    float*  dinvp      = (float*)(base + 401408);     // 400000 B
    uint32* classpairs = (uint32*)(base + 801536);    // 4,194,304 B
    uint32* subpairs   = (uint32*)(base + 4996096);   // 4,718,592 B
    unsigned short* xb = (unsigned short*)(base + 9714944);  // 12,800,000 B
    float* out = (float*)d_out;

    // zero deg + classcur + subcur in one shot
    (void)hipMemsetAsync(base, 0, 401056, stream);

    binclass_kernel<<<512, 256, 0, stream>>>(row, col, deg_i, classcur, classpairs);
    dinv_kernel<<<(N_L + 255) / 256, 256, 0, stream>>>(deg_i, dinvp, N_L);
    xbconv_kernel<<<2048, 256, 0, stream>>>(x_local, dinvp, xb);
    binsub_kernel<<<NCLS * BINSUB_BPC, 256, 0, stream>>>(
        classcur, classpairs, subcur, subpairs);
    gather_epi_kernel<<<NGSB, 1024, 118592, stream>>>(
        xb, subpairs, subcur, dinvp, W_gcn, b_gcn, W_lin, b_lin, out);
}

// Round 12
// 214.563 us; speedup vs baseline: 2.4497x; 1.0330x over previous
//
#include <hip/hip_runtime.h>

#define N_L 100000
#define N_V 1000
#define D_IN 64
#define HCH 64
#define D_OUT 32
#define E_LL 1000000

#define NCLS 8
#define DST_PER_CLS 12500        // N_L / 8
#define CLSCAP 131072            // class list capacity
#define GW 400                   // gather-bin node width
#define NSB 32                   // gather bins per class
#define NGSB 256                 // total gather bins = 1 block per CU
#define SUBCAP 4608              // per-bin pair capacity (mean 3906, +11 sigma)

#define L1CAP 768                // no-reject: 511 + 256 <= 767
#define L1THR 512
#define L2CAP 384                // no-reject: 127 + 256 <= 383
#define L2THR 128
#define BINSUB_BPC 64            // binsub blocks per class (512 total)

typedef unsigned int uint32;
typedef unsigned long long u64;
typedef __attribute__((ext_vector_type(8))) short bfx8;    // 8 bf16 (4 VGPR)
typedef __attribute__((ext_vector_type(4))) float f32x4;   // MFMA C/D frag
typedef __attribute__((ext_vector_type(4))) float fvec4;
typedef __attribute__((ext_vector_type(4))) unsigned short usvec4;

__device__ inline float bf2f(unsigned short u) {
    return __uint_as_float(((uint32)u) << 16);
}
__device__ inline unsigned short f2bf(float f) {   // round-to-nearest-even
    uint32 u = __float_as_uint(f);
    u = (u + 0x7fffu + ((u >> 16) & 1u)) >> 16;
    return (unsigned short)u;
}
// LDS-only barrier: does NOT drain vmcnt (global stores/atomics stay in
// flight). All cross-wave state in these kernels is LDS (lgkmcnt-tracked).
__device__ inline void bar_lds() {
    asm volatile("s_waitcnt lgkmcnt(0)\n\ts_barrier" ::: "memory");
}

// ---- level-1: edge scan -> class-binned COO (NO global atomics) ----------
// pack = (r << 14) | (c - cls*12500).  Wave-aggregated slot allocation.
__global__ __launch_bounds__(256) void binclass_kernel(
    const int* __restrict__ row, const int* __restrict__ col,
    int* __restrict__ classcur, uint32* __restrict__ classpairs)
{
    __shared__ uint32 sbin[NCLS][L1CAP];
    __shared__ int scnt[NCLS];
    if (threadIdx.x < NCLS) scnt[threadIdx.x] = 0;
    bar_lds();

    const int per = (E_LL + gridDim.x - 1) / gridDim.x;
    const int beg = blockIdx.x * per;
    const int end = (beg + per < E_LL) ? beg + per : E_LL;
    const int lane = threadIdx.x & 63;
    const int wv = threadIdx.x >> 6;

    for (int i0 = beg; i0 < end; i0 += 256) {
        int i = i0 + threadIdx.x;
        if (i < end) {
            int c = col[i];
            int r = row[i];
            int cls = c / DST_PER_CLS;
            uint32 pack = ((uint32)r << 14) | (uint32)(c - cls * DST_PER_CLS);
            u64 act = __ballot(1);
            u64 b0 = __ballot(cls & 1);
            u64 b1 = __ballot(cls & 2);
            u64 b2 = __ballot(cls & 4);
            u64 mask = ((cls & 1) ? b0 : ~b0) & ((cls & 2) ? b1 : ~b1)
                     & ((cls & 4) ? b2 : ~b2) & act;
            int leader = __ffsll(mask) - 1;
            int rank = __popcll(mask & ((1ull << lane) - 1ull));
            int base = 0;
            if (lane == leader) base = atomicAdd(&scnt[cls], __popcll(mask));
            base = __shfl(base, leader);
            sbin[cls][base + rank] = pack;
        }
        bar_lds();
        for (int b = wv; b < NCLS; b += 4) {
            int cnt = scnt[b];
            if (cnt >= L1THR) {
                int gb;
                if (lane == 0) gb = atomicAdd(&classcur[b], cnt);
                gb = __shfl(gb, 0);
                uint32* dst = classpairs + (size_t)b * CLSCAP;
                for (int k = lane; k < cnt; k += 64)
                    if (gb + k < CLSCAP) dst[gb + k] = sbin[b][k];
                if (lane == 0) scnt[b] = 0;
            }
        }
        bar_lds();
    }
    for (int b = wv; b < NCLS; b += 4) {   // final flush
        int cnt = scnt[b];
        if (cnt > 0) {
            int gb;
            if (lane == 0) gb = atomicAdd(&classcur[b], cnt);
            gb = __shfl(gb, 0);
            uint32* dst = classpairs + (size_t)b * CLSCAP;
            for (int k = lane; k < cnt; k += 64)
                if (gb + k < CLSCAP) dst[gb + k] = sbin[b][k];
        }
    }
}

// ---- level-2: class COO -> 32 gather-bins per class (wave-aggregated) ----
// pack2 = (r << 9) | (c_lo - sb*400)
__global__ __launch_bounds__(256) void binsub_kernel(
    const int* __restrict__ classcur, const uint32* __restrict__ classpairs,
    int* __restrict__ subcur, uint32* __restrict__ subpairs)
{
    __shared__ uint32 sbin[NSB][L2CAP];
    __shared__ int scnt[NSB];
    if (threadIdx.x < NSB) scnt[threadIdx.x] = 0;
    bar_lds();

    const int cls = blockIdx.x / BINSUB_BPC;
    const int chunk = blockIdx.x % BINSUB_BPC;
    int len = classcur[cls]; if (len > CLSCAP) len = CLSCAP;
    const int beg = (int)((long long)len * chunk / BINSUB_BPC);
    const int end = (int)((long long)len * (chunk + 1) / BINSUB_BPC);
    const uint32* cp = classpairs + (size_t)cls * CLSCAP;
    const int lane = threadIdx.x & 63;
    const int wv = threadIdx.x >> 6;

    for (int i0 = beg; i0 < end; i0 += 256) {
        int i = i0 + threadIdx.x;
        if (i < end) {
            uint32 p = cp[i];
            int c_lo = (int)(p & 16383u);
            uint32 r = p >> 14;
            int sb = c_lo / GW;
            uint32 pack = (r << 9) | (uint32)(c_lo - sb * GW);
            u64 act = __ballot(1);
            u64 b0 = __ballot(sb & 1);
            u64 b1 = __ballot(sb & 2);
            u64 b2 = __ballot(sb & 4);
            u64 b3 = __ballot(sb & 8);
            u64 b4 = __ballot(sb & 16);
            u64 mask = ((sb & 1) ? b0 : ~b0) & ((sb & 2) ? b1 : ~b1)
                     & ((sb & 4) ? b2 : ~b2) & ((sb & 8) ? b3 : ~b3)
                     & ((sb & 16) ? b4 : ~b4) & act;
            int leader = __ffsll(mask) - 1;
            int rank = __popcll(mask & ((1ull << lane) - 1ull));
            int base = 0;
            if (lane == leader) base = atomicAdd(&scnt[sb], __popcll(mask));
            base = __shfl(base, leader);
            sbin[sb][base + rank] = pack;
        }
        bar_lds();
        for (int b = wv; b < NSB; b += 4) {
            int cnt = scnt[b];
            if (cnt >= L2THR) {
                int gb;
                int gsb = cls * NSB + b;
                if (lane == 0) gb = atomicAdd(&subcur[gsb], cnt);
                gb = __shfl(gb, 0);
                uint32* dst = subpairs + (size_t)gsb * SUBCAP;
                for (int k = lane; k < cnt; k += 64)
                    if (gb + k < SUBCAP) dst[gb + k] = sbin[b][k];
                if (lane == 0) scnt[b] = 0;
            }
        }
        bar_lds();
    }
    for (int b = wv; b < NSB; b += 4) {   // final flush
        int cnt = scnt[b];
        if (cnt > 0) {
            int gb;
            int gsb = cls * NSB + b;
            if (lane == 0) gb = atomicAdd(&subcur[gsb], cnt);
            gb = __shfl(gb, 0);
            uint32* dst = subpairs + (size_t)gsb * SUBCAP;
            for (int k = lane; k < cnt; k += 64)
                if (gb + k < SUBCAP) dst[gb + k] = sbin[b][k];
        }
    }
}

// ---- deg/dinv from binned data (replaces 1M global deg atomics) ----------
// bins partition edges by dst, so per-bin histogram == deg.
__global__ __launch_bounds__(512) void degdinv_kernel(
    const uint32* __restrict__ subpairs, const int* __restrict__ subcur,
    float* __restrict__ dinv)
{
    __shared__ int hcnt[512];
    const int gsb = blockIdx.x;
    const int cls = gsb >> 5;
    const int sb = gsb & 31;
    const int lo = cls * DST_PER_CLS + sb * GW;
    int w = DST_PER_CLS - sb * GW; if (w > GW) w = GW;

    hcnt[threadIdx.x] = 0;
    bar_lds();
    int cnt = subcur[gsb]; if (cnt > SUBCAP) cnt = SUBCAP;
    const uint32* sp = subpairs + (size_t)gsb * SUBCAP;
    for (int i = threadIdx.x; i < cnt; i += 512)
        atomicAdd(&hcnt[sp[i] & 511u], 1);
    bar_lds();
    if (threadIdx.x < w) {
        int d = hcnt[threadIdx.x];
        dinv[lo + threadIdx.x] = (d > 0) ? rsqrtf((float)d) : 0.0f;
    }
}

// ---- xb[r,:] = bf16(x[r,:] * dinv[r]) ------------------------------------
__global__ void xbconv_kernel(const float* __restrict__ x,
                              const float* __restrict__ dinv,
                              unsigned short* __restrict__ xb) {
    int n4 = N_L * D_IN / 4;
    int idx = blockIdx.x * blockDim.x + threadIdx.x;
    int stride = gridDim.x * blockDim.x;
    for (; idx < n4; idx += stride) {
        fvec4 v = ((const fvec4*)x)[idx];
        float d = dinv[idx >> 4];
        usvec4 o;
        o.x = f2bf(v.x * d);
        o.y = f2bf(v.y * d);
        o.z = f2bf(v.z * d);
        o.w = f2bf(v.w * d);
        ((usvec4*)xb)[idx] = o;
    }
}

// ---- gather + fused epilogue: counting sort + register accumulation ------
__global__ __launch_bounds__(1024) void gather_epi_kernel(
    const unsigned short* __restrict__ xb,
    const uint32* __restrict__ subpairs, const int* __restrict__ subcur,
    const float* __restrict__ Wg, const float* __restrict__ bg,
    const float* __restrict__ Wl, const float* __restrict__ bl,
    float* __restrict__ out)
{
    extern __shared__ char smem[];
    unsigned short* hacc = (unsigned short*)smem;              // [400][72] bf16
    unsigned short* hbufp = (unsigned short*)(smem + 57600);   // [16][16][72]
    uint32* sorted = (uint32*)(smem + 94464);                  // [SUBCAP]
    int* rptr  = (int*)(smem + 112896);                        // [512]
    int* scan2 = (int*)(smem + 114944);                        // [512]
    int* cur   = (int*)(smem + 116992);                        // [400]

    const int gsb = blockIdx.x;
    const int cls = gsb >> 5;
    const int sb = gsb & 31;
    const int lo = cls * DST_PER_CLS + sb * GW;
    int w = DST_PER_CLS - sb * GW; if (w > GW) w = GW;    // 400 or 100

    const int tid = threadIdx.x;
    const int lane = tid & 63;
    const int wv = tid >> 6;

    int cnt = subcur[gsb]; if (cnt > SUBCAP) cnt = SUBCAP;
    const uint32* sp = subpairs + (size_t)gsb * SUBCAP;

    // (1) count
    if (tid < 512) rptr[tid] = 0;
    bar_lds();
    for (int i = tid; i < cnt; i += 1024)
        atomicAdd(&rptr[sp[i] & 511u], 1);
    bar_lds();

    // (2) exclusive scan over 512 (Hillis-Steele)
    int v = (tid < 512) ? rptr[tid] : 0;
    if (tid < 512) scan2[tid] = v;
    bar_lds();
    for (int ofs = 1; ofs < 512; ofs <<= 1) {
        int add = (tid < 512 && tid >= ofs) ? scan2[tid - ofs] : 0;
        bar_lds();
        if (tid < 512) scan2[tid] += add;
        bar_lds();
    }
    if (tid < 512) {
        int ex = scan2[tid] - v;
        rptr[tid] = ex;
        if (tid < 400) cur[tid] = ex;
    }
    bar_lds();

    // (3) place
    for (int i = tid; i < cnt; i += 1024) {
        uint32 p = sp[i];
        int pos = atomicAdd(&cur[p & 511u], 1);
        sorted[pos] = p >> 9;           // r
    }
    bar_lds();

    // (4) per-node register accumulation (ILP-8); dinv[c] = rsqrt(count)
    for (int c = wv; c < w; c += 16) {
        int s = rptr[c], e = rptr[c + 1];
        int cntc = e - s;
        float a0 = 0.f, a1 = 0.f, a2 = 0.f, a3 = 0.f;
        float a4 = 0.f, a5 = 0.f, a6 = 0.f, a7 = 0.f;
        int j = s;
        for (; j + 8 <= e; j += 8) {
            int r0 = sorted[j], r1 = sorted[j + 1];
            int r2 = sorted[j + 2], r3 = sorted[j + 3];
            int r4 = sorted[j + 4], r5 = sorted[j + 5];
            int r6 = sorted[j + 6], r7 = sorted[j + 7];
            a0 += bf2f(xb[(size_t)r0 * D_IN + lane]);
            a1 += bf2f(xb[(size_t)r1 * D_IN + lane]);
            a2 += bf2f(xb[(size_t)r2 * D_IN + lane]);
            a3 += bf2f(xb[(size_t)r3 * D_IN + lane]);
            a4 += bf2f(xb[(size_t)r4 * D_IN + lane]);
            a5 += bf2f(xb[(size_t)r5 * D_IN + lane]);
            a6 += bf2f(xb[(size_t)r6 * D_IN + lane]);
            a7 += bf2f(xb[(size_t)r7 * D_IN + lane]);
        }
        for (; j < e; ++j) {
            int r = sorted[j];
            a0 += bf2f(xb[(size_t)r * D_IN + lane]);
        }
        float dv = (cntc > 0) ? rsqrtf((float)cntc) : 0.0f;
        float s01 = (a0 + a1) + (a2 + a3);
        float s23 = (a4 + a5) + (a6 + a7);
        hacc[c * 72 + lane] = f2bf((s01 + s23) * dv);
    }
    bar_lds();

    // (5) MFMA epilogue
    const int lm = lane & 15, lg = lane >> 4, kseg = lg * 8;

    bfx8 wg0[4], wg1[4], wl0[2], wl1[2];
    #pragma unroll
    for (int n = 0; n < 4; ++n) {
        #pragma unroll
        for (int jj = 0; jj < 8; ++jj) {
            wg0[n][jj] = (short)f2bf(Wg[(kseg + jj) * HCH + n * 16 + lm]);
            wg1[n][jj] = (short)f2bf(Wg[(32 + kseg + jj) * HCH + n * 16 + lm]);
        }
    }
    #pragma unroll
    for (int n = 0; n < 2; ++n) {
        #pragma unroll
        for (int jj = 0; jj < 8; ++jj) {
            wl0[n][jj] = (short)f2bf(Wl[(kseg + jj) * D_OUT + n * 16 + lm]);
            wl1[n][jj] = (short)f2bf(Wl[(32 + kseg + jj) * D_OUT + n * 16 + lm]);
        }
    }
    float bgv[4], blv[2];
    #pragma unroll
    for (int n = 0; n < 4; ++n) bgv[n] = bg[n * 16 + lm];
    #pragma unroll
    for (int n = 0; n < 2; ++n) blv[n] = bl[n * 16 + lm];

    const int ntile = (w + 15) >> 4;
    for (int t = wv; t < ntile; t += 16) {
        const int m0 = t * 16;
        const int arow = m0 + lm;       // rows >= w read garbage; masked on store
        const unsigned short* fr = hacc + arow * 72;
        bfx8 a0 = *(const bfx8*)(fr + kseg);
        bfx8 a1 = *(const bfx8*)(fr + 32 + kseg);

        unsigned short* hb = hbufp + wv * (16 * 72);
        #pragma unroll
        for (int n = 0; n < 4; ++n) {
            f32x4 cacc = {0.0f, 0.0f, 0.0f, 0.0f};
            cacc = __builtin_amdgcn_mfma_f32_16x16x32_bf16(a0, wg0[n], cacc, 0, 0, 0);
            cacc = __builtin_amdgcn_mfma_f32_16x16x32_bf16(a1, wg1[n], cacc, 0, 0, 0);
            #pragma unroll
            for (int i = 0; i < 4; ++i) {
                float h = fmaxf(cacc[i] + bgv[n], 0.0f);
                hb[(lg * 4 + i) * 72 + n * 16 + lm] = f2bf(h);
            }
        }
        bfx8 a20 = *(const bfx8*)(hb + lm * 72 + kseg);
        bfx8 a21 = *(const bfx8*)(hb + lm * 72 + 32 + kseg);

        #pragma unroll
        for (int n2 = 0; n2 < 2; ++n2) {
            f32x4 d = {0.0f, 0.0f, 0.0f, 0.0f};
            d = __builtin_amdgcn_mfma_f32_16x16x32_bf16(a20, wl0[n2], d, 0, 0, 0);
            d = __builtin_amdgcn_mfma_f32_16x16x32_bf16(a21, wl1[n2], d, 0, 0, 0);
            #pragma unroll
            for (int i = 0; i < 4; ++i) {
                int mrow = m0 + lg * 4 + i;
                if (mrow < w)
                    out[(size_t)(lo + mrow) * D_OUT + n2 * 16 + lm] = d[i] + blv[n2];
            }
        }
    }
}

extern "C" void kernel_launch(void* const* d_in, const int* in_sizes, int n_in,
                              void* d_out, int out_size, void* d_ws, size_t ws_size,
                              hipStream_t stream) {
    const float* x_local = (const float*)d_in[0];
    const float* W_gcn   = (const float*)d_in[2];
    const float* b_gcn   = (const float*)d_in[3];
    const float* W_lin   = (const float*)d_in[10];
    const float* b_lin   = (const float*)d_in[11];
    const int*   edge_ll = (const int*)d_in[12];
    const int*   row = edge_ll;           // edge_ll[0, :]
    const int*   col = edge_ll + E_LL;    // edge_ll[1, :]

    // workspace layout (~22.1 MB)
    char* base = (char*)d_ws;
    int*    classcur   = (int*)(base + 0);            // 32 B
    int*    subcur     = (int*)(base + 128);          // 1024 B
    float*  dinvp      = (float*)(base + 2048);       // 400000 B
    uint32* classpairs = (uint32*)(base + 402048);    // 4,194,304 B
    uint32* subpairs   = (uint32*)(base + 4596352);   // 4,718,592 B
    unsigned short* xb = (unsigned short*)(base + 9314944);  // 12,800,000 B
    float* out = (float*)d_out;

    (void)hipMemsetAsync(base, 0, 1152, stream);   // classcur + subcur

    binclass_kernel<<<1024, 256, 0, stream>>>(row, col, classcur, classpairs);
    binsub_kernel<<<NCLS * BINSUB_BPC, 256, 0, stream>>>(
        classcur, classpairs, subcur, subpairs);
    degdinv_kernel<<<NGSB, 512, 0, stream>>>(subpairs, subcur, dinvp);
    xbconv_kernel<<<2048, 256, 0, stream>>>(x_local, dinvp, xb);
    gather_epi_kernel<<<NGSB, 1024, 118592, stream>>>(
        xb, subpairs, subcur, W_gcn, b_gcn, W_lin, b_lin, out);
}

// Round 13
// 112.379 us; speedup vs baseline: 4.6771x; 1.9093x over previous
//
#include <hip/hip_runtime.h>

#define N_L 100000
#define N_V 1000
#define D_IN 64
#define HCH 64
#define D_OUT 32
#define E_LL 1000000

#define NCLS 8
#define DST_PER_CLS 12500        // N_L / 8
#define NBLK1 1024               // binclass grid
#define BCAP 256                 // slab cap per (cls,blk): mean 122, +13 sigma
#define GW 400                   // gather-bin node width
#define NSB 32                   // gather bins per class
#define NGSB 256                 // total gather bins = 1 block per CU
#define SUBCAP 4608              // per-bin pair capacity (mean 3906, +11 sigma)
#define SCSTRIDE 16              // subcur padding: 1 cursor per 64B line

#define L2CAP 384                // no-reject: 127 + 256 <= 383
#define L2THR 128
#define BINSUB_BPC 64            // binsub blocks per class (512 total)
#define SLABS (NBLK1 / BINSUB_BPC)   // 16 slabs per binsub block

typedef unsigned int uint32;
typedef unsigned long long u64;
typedef __attribute__((ext_vector_type(8))) short bfx8;    // 8 bf16 (4 VGPR)
typedef __attribute__((ext_vector_type(4))) float f32x4;   // MFMA C/D frag
typedef __attribute__((ext_vector_type(4))) float fvec4;
typedef __attribute__((ext_vector_type(4))) unsigned short usvec4;

__device__ inline float bf2f(unsigned short u) {
    return __uint_as_float(((uint32)u) << 16);
}
__device__ inline unsigned short f2bf(float f) {   // round-to-nearest-even
    uint32 u = __float_as_uint(f);
    u = (u + 0x7fffu + ((u >> 16) & 1u)) >> 16;
    return (unsigned short)u;
}
// LDS-only barrier: does NOT drain vmcnt (global stores stay in flight).
__device__ inline void bar_lds() {
    asm volatile("s_waitcnt lgkmcnt(0)\n\ts_barrier" ::: "memory");
}

// ---- level-1: edge scan -> per-block class slabs (ZERO global atomics) ---
// pack = (r << 14) | (c - cls*12500). Each block owns edges [blk*977, ...)
// and writes its own slab classpairs[cls][blk][BCAP] + classcnt — plain
// coalesced stores, no cursor. (Round-12 lesson: 8192 same-line global
// RMWs on classcur serialized ~100us.)
__global__ __launch_bounds__(256) void binclass_kernel(
    const int* __restrict__ row, const int* __restrict__ col,
    int* __restrict__ classcnt, uint32* __restrict__ classpairs)
{
    __shared__ uint32 sbin[NCLS][BCAP];
    __shared__ int scnt[NCLS];
    if (threadIdx.x < NCLS) scnt[threadIdx.x] = 0;
    bar_lds();

    const int blk = blockIdx.x;
    const int per = (E_LL + NBLK1 - 1) / NBLK1;   // 977
    const int beg = blk * per;
    const int end = (beg + per < E_LL) ? beg + per : E_LL;
    const int lane = threadIdx.x & 63;
    const int wv = threadIdx.x >> 6;

    for (int i0 = beg; i0 < end; i0 += 256) {
        int i = i0 + threadIdx.x;
        if (i < end) {
            int c = col[i];
            int r = row[i];
            int cls = c / DST_PER_CLS;
            uint32 pack = ((uint32)r << 14) | (uint32)(c - cls * DST_PER_CLS);
            u64 act = __ballot(1);
            u64 b0 = __ballot(cls & 1);
            u64 b1 = __ballot(cls & 2);
            u64 b2 = __ballot(cls & 4);
            u64 mask = ((cls & 1) ? b0 : ~b0) & ((cls & 2) ? b1 : ~b1)
                     & ((cls & 4) ? b2 : ~b2) & act;
            int leader = __ffsll(mask) - 1;
            int rank = __popcll(mask & ((1ull << lane) - 1ull));
            int base = 0;
            if (lane == leader) base = atomicAdd(&scnt[cls], __popcll(mask));
            base = __shfl(base, leader);
            int slot = base + rank;
            if (slot < BCAP) sbin[cls][slot] = pack;   // overflow-guard
        }
    }
    bar_lds();
    for (int b = wv; b < NCLS; b += 4) {   // slab writeout (plain stores)
        int cnt = scnt[b]; if (cnt > BCAP) cnt = BCAP;
        uint32* dst = classpairs + ((size_t)b * NBLK1 + blk) * BCAP;
        for (int k = lane; k < cnt; k += 64) dst[k] = sbin[b][k];
        if (lane == 0) classcnt[b * NBLK1 + blk] = cnt;
    }
}

// ---- level-2: class slabs -> 32 gather-bins per class --------------------
// pack2 = (r << 9) | (c_lo - sb*400). One slab (<=256) per insert round
// preserves the no-reject bound (127 + 256 <= 383). subcur is line-padded.
__global__ __launch_bounds__(256) void binsub_kernel(
    const int* __restrict__ classcnt, const uint32* __restrict__ classpairs,
    int* __restrict__ subcur, uint32* __restrict__ subpairs)
{
    __shared__ uint32 sbin[NSB][L2CAP];
    __shared__ int scnt[NSB];
    if (threadIdx.x < NSB) scnt[threadIdx.x] = 0;
    bar_lds();

    const int cls = blockIdx.x / BINSUB_BPC;
    const int chunk = blockIdx.x % BINSUB_BPC;
    const int s0 = chunk * SLABS;
    const int lane = threadIdx.x & 63;
    const int wv = threadIdx.x >> 6;

    for (int s = s0; s < s0 + SLABS; ++s) {
        int len = classcnt[cls * NBLK1 + s];
        const uint32* cp = classpairs + ((size_t)cls * NBLK1 + s) * BCAP;
        if (threadIdx.x < len) {
            uint32 p = cp[threadIdx.x];
            int c_lo = (int)(p & 16383u);
            uint32 r = p >> 14;
            int sb = c_lo / GW;
            uint32 pack = (r << 9) | (uint32)(c_lo - sb * GW);
            u64 act = __ballot(1);
            u64 b0 = __ballot(sb & 1);
            u64 b1 = __ballot(sb & 2);
            u64 b2 = __ballot(sb & 4);
            u64 b3 = __ballot(sb & 8);
            u64 b4 = __ballot(sb & 16);
            u64 mask = ((sb & 1) ? b0 : ~b0) & ((sb & 2) ? b1 : ~b1)
                     & ((sb & 4) ? b2 : ~b2) & ((sb & 8) ? b3 : ~b3)
                     & ((sb & 16) ? b4 : ~b4) & act;
            int leader = __ffsll(mask) - 1;
            int rank = __popcll(mask & ((1ull << lane) - 1ull));
            int base = 0;
            if (lane == leader) base = atomicAdd(&scnt[sb], __popcll(mask));
            base = __shfl(base, leader);
            sbin[sb][base + rank] = pack;
        }
        bar_lds();
        for (int b = wv; b < NSB; b += 4) {
            int cnt = scnt[b];
            if (cnt >= L2THR) {
                int gb;
                int gsb = cls * NSB + b;
                if (lane == 0) gb = atomicAdd(&subcur[gsb * SCSTRIDE], cnt);
                gb = __shfl(gb, 0);
                uint32* dst = subpairs + (size_t)gsb * SUBCAP;
                for (int k = lane; k < cnt; k += 64)
                    if (gb + k < SUBCAP) dst[gb + k] = sbin[b][k];
                if (lane == 0) scnt[b] = 0;
            }
        }
        bar_lds();
    }
    for (int b = wv; b < NSB; b += 4) {   // final flush
        int cnt = scnt[b];
        if (cnt > 0) {
            int gb;
            int gsb = cls * NSB + b;
            if (lane == 0) gb = atomicAdd(&subcur[gsb * SCSTRIDE], cnt);
            gb = __shfl(gb, 0);
            uint32* dst = subpairs + (size_t)gsb * SUBCAP;
            for (int k = lane; k < cnt; k += 64)
                if (gb + k < SUBCAP) dst[gb + k] = sbin[b][k];
        }
    }
}

// ---- deg/dinv from binned data -------------------------------------------
__global__ __launch_bounds__(512) void degdinv_kernel(
    const uint32* __restrict__ subpairs, const int* __restrict__ subcur,
    float* __restrict__ dinv)
{
    __shared__ int hcnt[512];
    const int gsb = blockIdx.x;
    const int cls = gsb >> 5;
    const int sb = gsb & 31;
    const int lo = cls * DST_PER_CLS + sb * GW;
    int w = DST_PER_CLS - sb * GW; if (w > GW) w = GW;

    hcnt[threadIdx.x] = 0;
    bar_lds();
    int cnt = subcur[gsb * SCSTRIDE]; if (cnt > SUBCAP) cnt = SUBCAP;
    const uint32* sp = subpairs + (size_t)gsb * SUBCAP;
    for (int i = threadIdx.x; i < cnt; i += 512)
        atomicAdd(&hcnt[sp[i] & 511u], 1);
    bar_lds();
    if (threadIdx.x < w) {
        int d = hcnt[threadIdx.x];
        dinv[lo + threadIdx.x] = (d > 0) ? rsqrtf((float)d) : 0.0f;
    }
}

// ---- xb[r,:] = bf16(x[r,:] * dinv[r]) ------------------------------------
__global__ void xbconv_kernel(const float* __restrict__ x,
                              const float* __restrict__ dinv,
                              unsigned short* __restrict__ xb) {
    int n4 = N_L * D_IN / 4;
    int idx = blockIdx.x * blockDim.x + threadIdx.x;
    int stride = gridDim.x * blockDim.x;
    for (; idx < n4; idx += stride) {
        fvec4 v = ((const fvec4*)x)[idx];
        float d = dinv[idx >> 4];
        usvec4 o;
        o.x = f2bf(v.x * d);
        o.y = f2bf(v.y * d);
        o.z = f2bf(v.z * d);
        o.w = f2bf(v.w * d);
        ((usvec4*)xb)[idx] = o;
    }
}

// ---- gather + fused epilogue: counting sort + register accumulation ------
__global__ __launch_bounds__(1024) void gather_epi_kernel(
    const unsigned short* __restrict__ xb,
    const uint32* __restrict__ subpairs, const int* __restrict__ subcur,
    const float* __restrict__ Wg, const float* __restrict__ bg,
    const float* __restrict__ Wl, const float* __restrict__ bl,
    float* __restrict__ out)
{
    extern __shared__ char smem[];
    unsigned short* hacc = (unsigned short*)smem;              // [400][72] bf16
    unsigned short* hbufp = (unsigned short*)(smem + 57600);   // [16][16][72]
    uint32* sorted = (uint32*)(smem + 94464);                  // [SUBCAP]
    int* rptr  = (int*)(smem + 112896);                        // [512]
    int* scan2 = (int*)(smem + 114944);                        // [512]
    int* cur   = (int*)(smem + 116992);                        // [400]

    const int gsb = blockIdx.x;
    const int cls = gsb >> 5;
    const int sb = gsb & 31;
    const int lo = cls * DST_PER_CLS + sb * GW;
    int w = DST_PER_CLS - sb * GW; if (w > GW) w = GW;    // 400 or 100

    const int tid = threadIdx.x;
    const int lane = tid & 63;
    const int wv = tid >> 6;

    int cnt = subcur[gsb * SCSTRIDE]; if (cnt > SUBCAP) cnt = SUBCAP;
    const uint32* sp = subpairs + (size_t)gsb * SUBCAP;

    // (1) count
    if (tid < 512) rptr[tid] = 0;
    bar_lds();
    for (int i = tid; i < cnt; i += 1024)
        atomicAdd(&rptr[sp[i] & 511u], 1);
    bar_lds();

    // (2) exclusive scan over 512 (Hillis-Steele)
    int v = (tid < 512) ? rptr[tid] : 0;
    if (tid < 512) scan2[tid] = v;
    bar_lds();
    for (int ofs = 1; ofs < 512; ofs <<= 1) {
        int add = (tid < 512 && tid >= ofs) ? scan2[tid - ofs] : 0;
        bar_lds();
        if (tid < 512) scan2[tid] += add;
        bar_lds();
    }
    if (tid < 512) {
        int ex = scan2[tid] - v;
        rptr[tid] = ex;
        if (tid < 400) cur[tid] = ex;
    }
    bar_lds();

    // (3) place
    for (int i = tid; i < cnt; i += 1024) {
        uint32 p = sp[i];
        int pos = atomicAdd(&cur[p & 511u], 1);
        sorted[pos] = p >> 9;           // r
    }
    bar_lds();

    // (4) per-node register accumulation (ILP-8); dinv[c] = rsqrt(count)
    for (int c = wv; c < w; c += 16) {
        int s = rptr[c], e = rptr[c + 1];
        int cntc = e - s;
        float a0 = 0.f, a1 = 0.f, a2 = 0.f, a3 = 0.f;
        float a4 = 0.f, a5 = 0.f, a6 = 0.f, a7 = 0.f;
        int j = s;
        for (; j + 8 <= e; j += 8) {
            int r0 = sorted[j], r1 = sorted[j + 1];
            int r2 = sorted[j + 2], r3 = sorted[j + 3];
            int r4 = sorted[j + 4], r5 = sorted[j + 5];
            int r6 = sorted[j + 6], r7 = sorted[j + 7];
            a0 += bf2f(xb[(size_t)r0 * D_IN + lane]);
            a1 += bf2f(xb[(size_t)r1 * D_IN + lane]);
            a2 += bf2f(xb[(size_t)r2 * D_IN + lane]);
            a3 += bf2f(xb[(size_t)r3 * D_IN + lane]);
            a4 += bf2f(xb[(size_t)r4 * D_IN + lane]);
            a5 += bf2f(xb[(size_t)r5 * D_IN + lane]);
            a6 += bf2f(xb[(size_t)r6 * D_IN + lane]);
            a7 += bf2f(xb[(size_t)r7 * D_IN + lane]);
        }
        for (; j < e; ++j) {
            int r = sorted[j];
            a0 += bf2f(xb[(size_t)r * D_IN + lane]);
        }
        float dv = (cntc > 0) ? rsqrtf((float)cntc) : 0.0f;
        float s01 = (a0 + a1) + (a2 + a3);
        float s23 = (a4 + a5) + (a6 + a7);
        hacc[c * 72 + lane] = f2bf((s01 + s23) * dv);
    }
    bar_lds();

    // (5) MFMA epilogue
    const int lm = lane & 15, lg = lane >> 4, kseg = lg * 8;

    bfx8 wg0[4], wg1[4], wl0[2], wl1[2];
    #pragma unroll
    for (int n = 0; n < 4; ++n) {
        #pragma unroll
        for (int jj = 0; jj < 8; ++jj) {
            wg0[n][jj] = (short)f2bf(Wg[(kseg + jj) * HCH + n * 16 + lm]);
            wg1[n][jj] = (short)f2bf(Wg[(32 + kseg + jj) * HCH + n * 16 + lm]);
        }
    }
    #pragma unroll
    for (int n = 0; n < 2; ++n) {
        #pragma unroll
        for (int jj = 0; jj < 8; ++jj) {
            wl0[n][jj] = (short)f2bf(Wl[(kseg + jj) * D_OUT + n * 16 + lm]);
            wl1[n][jj] = (short)f2bf(Wl[(32 + kseg + jj) * D_OUT + n * 16 + lm]);
        }
    }
    float bgv[4], blv[2];
    #pragma unroll
    for (int n = 0; n < 4; ++n) bgv[n] = bg[n * 16 + lm];
    #pragma unroll
    for (int n = 0; n < 2; ++n) blv[n] = bl[n * 16 + lm];

    const int ntile = (w + 15) >> 4;
    for (int t = wv; t < ntile; t += 16) {
        const int m0 = t * 16;
        const int arow = m0 + lm;       // rows >= w read garbage; masked on store
        const unsigned short* fr = hacc + arow * 72;
        bfx8 a0 = *(const bfx8*)(fr + kseg);
        bfx8 a1 = *(const bfx8*)(fr + 32 + kseg);

        unsigned short* hb = hbufp + wv * (16 * 72);
        #pragma unroll
        for (int n = 0; n < 4; ++n) {
            f32x4 cacc = {0.0f, 0.0f, 0.0f, 0.0f};
            cacc = __builtin_amdgcn_mfma_f32_16x16x32_bf16(a0, wg0[n], cacc, 0, 0, 0);
            cacc = __builtin_amdgcn_mfma_f32_16x16x32_bf16(a1, wg1[n], cacc, 0, 0, 0);
            #pragma unroll
            for (int i = 0; i < 4; ++i) {
                float h = fmaxf(cacc[i] + bgv[n], 0.0f);
                hb[(lg * 4 + i) * 72 + n * 16 + lm] = f2bf(h);
            }
        }
        bfx8 a20 = *(const bfx8*)(hb + lm * 72 + kseg);
        bfx8 a21 = *(const bfx8*)(hb + lm * 72 + 32 + kseg);

        #pragma unroll
        for (int n2 = 0; n2 < 2; ++n2) {
            f32x4 d = {0.0f, 0.0f, 0.0f, 0.0f};
            d = __builtin_amdgcn_mfma_f32_16x16x32_bf16(a20, wl0[n2], d, 0, 0, 0);
            d = __builtin_amdgcn_mfma_f32_16x16x32_bf16(a21, wl1[n2], d, 0, 0, 0);
            #pragma unroll
            for (int i = 0; i < 4; ++i) {
                int mrow = m0 + lg * 4 + i;
                if (mrow < w)
                    out[(size_t)(lo + mrow) * D_OUT + n2 * 16 + lm] = d[i] + blv[n2];
            }
        }
    }
}

extern "C" void kernel_launch(void* const* d_in, const int* in_sizes, int n_in,
                              void* d_out, int out_size, void* d_ws, size_t ws_size,
                              hipStream_t stream) {
    const float* x_local = (const float*)d_in[0];
    const float* W_gcn   = (const float*)d_in[2];
    const float* b_gcn   = (const float*)d_in[3];
    const float* W_lin   = (const float*)d_in[10];
    const float* b_lin   = (const float*)d_in[11];
    const int*   edge_ll = (const int*)d_in[12];
    const int*   row = edge_ll;           // edge_ll[0, :]
    const int*   col = edge_ll + E_LL;    // edge_ll[1, :]

    // workspace layout (~25.1 MB)
    char* base = (char*)d_ws;
    int*    subcur     = (int*)(base + 0);            // 16,384 B (padded)
    int*    classcnt   = (int*)(base + 16384);        // 32,768 B
    float*  dinvp      = (float*)(base + 49152);      // 400,000 B
    uint32* classpairs = (uint32*)(base + 449536);    // 8,388,608 B
    uint32* subpairs   = (uint32*)(base + 8838144);   // 4,718,592 B
    unsigned short* xb = (unsigned short*)(base + 13556736);  // 12,800,000 B
    float* out = (float*)d_out;

    (void)hipMemsetAsync(base, 0, 16384, stream);   // subcur only

    binclass_kernel<<<NBLK1, 256, 0, stream>>>(row, col, classcnt, classpairs);
    binsub_kernel<<<NCLS * BINSUB_BPC, 256, 0, stream>>>(
        classcnt, classpairs, subcur, subpairs);
    degdinv_kernel<<<NGSB, 512, 0, stream>>>(subpairs, subcur, dinvp);
    xbconv_kernel<<<2048, 256, 0, stream>>>(x_local, dinvp, xb);
    gather_epi_kernel<<<NGSB, 1024, 118592, stream>>>(
        xb, subpairs, subcur, W_gcn, b_gcn, W_lin, b_lin, out);
}

// Round 14
// 112.243 us; speedup vs baseline: 4.6828x; 1.0012x over previous
//
#include <hip/hip_runtime.h>

#define N_L 100000
#define N_V 1000
#define D_IN 64
#define HCH 64
#define D_OUT 32
#define E_LL 1000000

#define NCLS 8
#define DST_PER_CLS 12500        // N_L / 8
#define NBLK1 1024               // binclass grid
#define BCAP 256                 // slab cap per (cls,blk): mean 122, +13 sigma
#define GW 400                   // gather-bin node width
#define HW 200                   // gather half-bin node width
#define NSB 32                   // gather bins per class
#define NGSB 256                 // total gather bins
#define SUBCAP 4608              // per-bin pair capacity (mean 3906, +11 sigma)
#define SORTCAP 2560             // per-half-bin sorted cap (mean 1953, +13 sigma)
#define SCSTRIDE 16              // subcur padding: 1 cursor per 64B line

#define L2CAP 384                // no-reject: 127 + 256 <= 383
#define L2THR 128
#define BINSUB_BPC 64            // binsub blocks per class (512 total)
#define SLABS (NBLK1 / BINSUB_BPC)   // 16 slabs per binsub block

typedef unsigned int uint32;
typedef unsigned long long u64;
typedef __attribute__((ext_vector_type(8))) short bfx8;    // 8 bf16 (4 VGPR)
typedef __attribute__((ext_vector_type(4))) float f32x4;   // MFMA C/D frag
typedef __attribute__((ext_vector_type(4))) float fvec4;
typedef __attribute__((ext_vector_type(4))) unsigned short usvec4;

__device__ inline float bf2f(unsigned short u) {
    return __uint_as_float(((uint32)u) << 16);
}
__device__ inline unsigned short f2bf(float f) {   // round-to-nearest-even
    uint32 u = __float_as_uint(f);
    u = (u + 0x7fffu + ((u >> 16) & 1u)) >> 16;
    return (unsigned short)u;
}
// LDS-only barrier: does NOT drain vmcnt (global stores stay in flight).
__device__ inline void bar_lds() {
    asm volatile("s_waitcnt lgkmcnt(0)\n\ts_barrier" ::: "memory");
}

// ---- level-1: edge scan -> per-block class slabs (ZERO global atomics) ---
__global__ __launch_bounds__(256) void binclass_kernel(
    const int* __restrict__ row, const int* __restrict__ col,
    int* __restrict__ classcnt, uint32* __restrict__ classpairs)
{
    __shared__ uint32 sbin[NCLS][BCAP];
    __shared__ int scnt[NCLS];
    if (threadIdx.x < NCLS) scnt[threadIdx.x] = 0;
    bar_lds();

    const int blk = blockIdx.x;
    const int per = (E_LL + NBLK1 - 1) / NBLK1;   // 977
    const int beg = blk * per;
    const int end = (beg + per < E_LL) ? beg + per : E_LL;
    const int lane = threadIdx.x & 63;
    const int wv = threadIdx.x >> 6;

    for (int i0 = beg; i0 < end; i0 += 256) {
        int i = i0 + threadIdx.x;
        if (i < end) {
            int c = col[i];
            int r = row[i];
            int cls = c / DST_PER_CLS;
            uint32 pack = ((uint32)r << 14) | (uint32)(c - cls * DST_PER_CLS);
            u64 act = __ballot(1);
            u64 b0 = __ballot(cls & 1);
            u64 b1 = __ballot(cls & 2);
            u64 b2 = __ballot(cls & 4);
            u64 mask = ((cls & 1) ? b0 : ~b0) & ((cls & 2) ? b1 : ~b1)
                     & ((cls & 4) ? b2 : ~b2) & act;
            int leader = __ffsll(mask) - 1;
            int rank = __popcll(mask & ((1ull << lane) - 1ull));
            int base = 0;
            if (lane == leader) base = atomicAdd(&scnt[cls], __popcll(mask));
            base = __shfl(base, leader);
            int slot = base + rank;
            if (slot < BCAP) sbin[cls][slot] = pack;   // overflow-guard
        }
    }
    bar_lds();
    for (int b = wv; b < NCLS; b += 4) {   // slab writeout (plain stores)
        int cnt = scnt[b]; if (cnt > BCAP) cnt = BCAP;
        uint32* dst = classpairs + ((size_t)b * NBLK1 + blk) * BCAP;
        for (int k = lane; k < cnt; k += 64) dst[k] = sbin[b][k];
        if (lane == 0) classcnt[b * NBLK1 + blk] = cnt;
    }
}

// ---- level-2: class slabs -> 32 gather-bins per class --------------------
__global__ __launch_bounds__(256) void binsub_kernel(
    const int* __restrict__ classcnt, const uint32* __restrict__ classpairs,
    int* __restrict__ subcur, uint32* __restrict__ subpairs)
{
    __shared__ uint32 sbin[NSB][L2CAP];
    __shared__ int scnt[NSB];
    if (threadIdx.x < NSB) scnt[threadIdx.x] = 0;
    bar_lds();

    const int cls = blockIdx.x / BINSUB_BPC;
    const int chunk = blockIdx.x % BINSUB_BPC;
    const int s0 = chunk * SLABS;
    const int lane = threadIdx.x & 63;
    const int wv = threadIdx.x >> 6;

    for (int s = s0; s < s0 + SLABS; ++s) {
        int len = classcnt[cls * NBLK1 + s];
        const uint32* cp = classpairs + ((size_t)cls * NBLK1 + s) * BCAP;
        if (threadIdx.x < len) {
            uint32 p = cp[threadIdx.x];
            int c_lo = (int)(p & 16383u);
            uint32 r = p >> 14;
            int sb = c_lo / GW;
            uint32 pack = (r << 9) | (uint32)(c_lo - sb * GW);
            u64 act = __ballot(1);
            u64 b0 = __ballot(sb & 1);
            u64 b1 = __ballot(sb & 2);
            u64 b2 = __ballot(sb & 4);
            u64 b3 = __ballot(sb & 8);
            u64 b4 = __ballot(sb & 16);
            u64 mask = ((sb & 1) ? b0 : ~b0) & ((sb & 2) ? b1 : ~b1)
                     & ((sb & 4) ? b2 : ~b2) & ((sb & 8) ? b3 : ~b3)
                     & ((sb & 16) ? b4 : ~b4) & act;
            int leader = __ffsll(mask) - 1;
            int rank = __popcll(mask & ((1ull << lane) - 1ull));
            int base = 0;
            if (lane == leader) base = atomicAdd(&scnt[sb], __popcll(mask));
            base = __shfl(base, leader);
            sbin[sb][base + rank] = pack;
        }
        bar_lds();
        for (int b = wv; b < NSB; b += 4) {
            int cnt = scnt[b];
            if (cnt >= L2THR) {
                int gb;
                int gsb = cls * NSB + b;
                if (lane == 0) gb = atomicAdd(&subcur[gsb * SCSTRIDE], cnt);
                gb = __shfl(gb, 0);
                uint32* dst = subpairs + (size_t)gsb * SUBCAP;
                for (int k = lane; k < cnt; k += 64)
                    if (gb + k < SUBCAP) dst[gb + k] = sbin[b][k];
                if (lane == 0) scnt[b] = 0;
            }
        }
        bar_lds();
    }
    for (int b = wv; b < NSB; b += 4) {   // final flush
        int cnt = scnt[b];
        if (cnt > 0) {
            int gb;
            int gsb = cls * NSB + b;
            if (lane == 0) gb = atomicAdd(&subcur[gsb * SCSTRIDE], cnt);
            gb = __shfl(gb, 0);
            uint32* dst = subpairs + (size_t)gsb * SUBCAP;
            for (int k = lane; k < cnt; k += 64)
                if (gb + k < SUBCAP) dst[gb + k] = sbin[b][k];
        }
    }
}

// ---- deg/dinv + per-bin exclusive rowptr (computed ONCE, reused) ---------
__global__ __launch_bounds__(512) void degdinv_kernel(
    const uint32* __restrict__ subpairs, const int* __restrict__ subcur,
    float* __restrict__ dinv, int* __restrict__ rptrg)
{
    __shared__ int hcnt[512];
    __shared__ int scn[512];
    const int gsb = blockIdx.x;
    const int cls = gsb >> 5;
    const int sb = gsb & 31;
    const int lo = cls * DST_PER_CLS + sb * GW;
    int w = DST_PER_CLS - sb * GW; if (w > GW) w = GW;
    const int tid = threadIdx.x;

    hcnt[tid] = 0;
    bar_lds();
    int cnt = subcur[gsb * SCSTRIDE]; if (cnt > SUBCAP) cnt = SUBCAP;
    const uint32* sp = subpairs + (size_t)gsb * SUBCAP;
    for (int i = tid; i < cnt; i += 512)
        atomicAdd(&hcnt[sp[i] & 511u], 1);
    bar_lds();

    int v = hcnt[tid];
    scn[tid] = v;
    bar_lds();
    for (int ofs = 1; ofs < 512; ofs <<= 1) {
        int add = (tid >= ofs) ? scn[tid - ofs] : 0;
        bar_lds();
        scn[tid] += add;
        bar_lds();
    }
    rptrg[gsb * 512 + tid] = scn[tid] - v;   // exclusive scan
    if (tid < w)
        dinv[lo + tid] = (v > 0) ? rsqrtf((float)v) : 0.0f;
}

// ---- xb[r,:] = bf16(x[r,:] * dinv[r]) ------------------------------------
__global__ void xbconv_kernel(const float* __restrict__ x,
                              const float* __restrict__ dinv,
                              unsigned short* __restrict__ xb) {
    int n4 = N_L * D_IN / 4;
    int idx = blockIdx.x * blockDim.x + threadIdx.x;
    int stride = gridDim.x * blockDim.x;
    for (; idx < n4; idx += stride) {
        fvec4 v = ((const fvec4*)x)[idx];
        float d = dinv[idx >> 4];
        usvec4 o;
        o.x = f2bf(v.x * d);
        o.y = f2bf(v.y * d);
        o.z = f2bf(v.z * d);
        o.w = f2bf(v.w * d);
        ((usvec4*)xb)[idx] = o;
    }
}

// ---- gather + fused epilogue: half-bin blocks, precomputed rptr ----------
// 512 blocks x 512 threads (2 blocks/CU). Phases: load rptr (global) ->
// place (filtered) -> per-node register accumulate -> MFMA epilogue.
__global__ __launch_bounds__(512) void gather_epi_kernel(
    const unsigned short* __restrict__ xb,
    const uint32* __restrict__ subpairs, const int* __restrict__ subcur,
    const int* __restrict__ rptrg,
    const float* __restrict__ Wg, const float* __restrict__ bg,
    const float* __restrict__ Wl, const float* __restrict__ bl,
    float* __restrict__ out)
{
    extern __shared__ char smem[];
    unsigned short* hacc  = (unsigned short*)smem;            // [208][72] bf16
    unsigned short* hbufp = (unsigned short*)(smem + 29952);  // [8][16][72]
    uint32* sorted = (uint32*)(smem + 48384);                 // [SORTCAP]
    int* rptr_l = (int*)(smem + 58624);                       // [208]
    int* cur    = (int*)(smem + 59456);                       // [200]

    const int gsb = blockIdx.x >> 1;
    const int hb  = blockIdx.x & 1;
    const int cls = gsb >> 5;
    const int sb  = gsb & 31;
    const int lo_bin = cls * DST_PER_CLS + sb * GW;
    int wbin = DST_PER_CLS - sb * GW; if (wbin > GW) wbin = GW;  // 400 or 100
    const int lo_node = hb * HW;
    int w = wbin - lo_node; if (w > HW) w = HW; if (w < 0) w = 0;
    const int lo = lo_bin + lo_node;

    const int tid = threadIdx.x;
    const int lane = tid & 63;
    const int wv = tid >> 6;     // 0..7

    int cnt = subcur[gsb * SCSTRIDE]; if (cnt > SUBCAP) cnt = SUBCAP;
    const uint32* sp = subpairs + (size_t)gsb * SUBCAP;
    const int* rg = rptrg + gsb * 512;

    const int base0 = rg[lo_node];
    if (tid <= w) {
        int rl = rg[lo_node + tid] - base0;
        rptr_l[tid] = rl;
        if (tid < w) cur[tid] = rl;
    }
    bar_lds();

    // place (filter my half)
    for (int i = tid; i < cnt; i += 512) {
        uint32 p = sp[i];
        int cl = (int)(p & 511u) - lo_node;
        if (cl >= 0 && cl < w) {
            int pos = atomicAdd(&cur[cl], 1);
            if (pos < SORTCAP) sorted[pos] = p >> 9;
        }
    }
    bar_lds();

    // per-node register accumulation (ILP-8); dinv[c] = rsqrt(count)
    for (int c = wv; c < w; c += 8) {
        int s = rptr_l[c], e = rptr_l[c + 1];
        if (e > SORTCAP) e = SORTCAP;
        int cntc = e - s;
        float a0 = 0.f, a1 = 0.f, a2 = 0.f, a3 = 0.f;
        float a4 = 0.f, a5 = 0.f, a6 = 0.f, a7 = 0.f;
        int j = s;
        for (; j + 8 <= e; j += 8) {
            int r0 = sorted[j], r1 = sorted[j + 1];
            int r2 = sorted[j + 2], r3 = sorted[j + 3];
            int r4 = sorted[j + 4], r5 = sorted[j + 5];
            int r6 = sorted[j + 6], r7 = sorted[j + 7];
            a0 += bf2f(xb[(size_t)r0 * D_IN + lane]);
            a1 += bf2f(xb[(size_t)r1 * D_IN + lane]);
            a2 += bf2f(xb[(size_t)r2 * D_IN + lane]);
            a3 += bf2f(xb[(size_t)r3 * D_IN + lane]);
            a4 += bf2f(xb[(size_t)r4 * D_IN + lane]);
            a5 += bf2f(xb[(size_t)r5 * D_IN + lane]);
            a6 += bf2f(xb[(size_t)r6 * D_IN + lane]);
            a7 += bf2f(xb[(size_t)r7 * D_IN + lane]);
        }
        for (; j < e; ++j) {
            int r = sorted[j];
            a0 += bf2f(xb[(size_t)r * D_IN + lane]);
        }
        float dv = (cntc > 0) ? rsqrtf((float)cntc) : 0.0f;
        float s01 = (a0 + a1) + (a2 + a3);
        float s23 = (a4 + a5) + (a6 + a7);
        hacc[c * 72 + lane] = f2bf((s01 + s23) * dv);
    }
    bar_lds();

    if (w == 0) return;   // empty half of the tail bin

    // MFMA epilogue
    const int lm = lane & 15, lg = lane >> 4, kseg = lg * 8;

    bfx8 wg0[4], wg1[4], wl0[2], wl1[2];
    #pragma unroll
    for (int n = 0; n < 4; ++n) {
        #pragma unroll
        for (int jj = 0; jj < 8; ++jj) {
            wg0[n][jj] = (short)f2bf(Wg[(kseg + jj) * HCH + n * 16 + lm]);
            wg1[n][jj] = (short)f2bf(Wg[(32 + kseg + jj) * HCH + n * 16 + lm]);
        }
    }
    #pragma unroll
    for (int n = 0; n < 2; ++n) {
        #pragma unroll
        for (int jj = 0; jj < 8; ++jj) {
            wl0[n][jj] = (short)f2bf(Wl[(kseg + jj) * D_OUT + n * 16 + lm]);
            wl1[n][jj] = (short)f2bf(Wl[(32 + kseg + jj) * D_OUT + n * 16 + lm]);
        }
    }
    float bgv[4], blv[2];
    #pragma unroll
    for (int n = 0; n < 4; ++n) bgv[n] = bg[n * 16 + lm];
    #pragma unroll
    for (int n = 0; n < 2; ++n) blv[n] = bl[n * 16 + lm];

    const int ntile = (w + 15) >> 4;   // <= 13
    for (int t = wv; t < ntile; t += 8) {
        const int m0 = t * 16;
        const int arow = m0 + lm;       // rows >= w read garbage; masked on store
        const unsigned short* fr = hacc + arow * 72;
        bfx8 a0 = *(const bfx8*)(fr + kseg);
        bfx8 a1 = *(const bfx8*)(fr + 32 + kseg);

        unsigned short* hbw = hbufp + wv * (16 * 72);
        #pragma unroll
        for (int n = 0; n < 4; ++n) {
            f32x4 cacc = {0.0f, 0.0f, 0.0f, 0.0f};
            cacc = __builtin_amdgcn_mfma_f32_16x16x32_bf16(a0, wg0[n], cacc, 0, 0, 0);
            cacc = __builtin_amdgcn_mfma_f32_16x16x32_bf16(a1, wg1[n], cacc, 0, 0, 0);
            #pragma unroll
            for (int i = 0; i < 4; ++i) {
                float h = fmaxf(cacc[i] + bgv[n], 0.0f);
                hbw[(lg * 4 + i) * 72 + n * 16 + lm] = f2bf(h);
            }
        }
        bfx8 a20 = *(const bfx8*)(hbw + lm * 72 + kseg);
        bfx8 a21 = *(const bfx8*)(hbw + lm * 72 + 32 + kseg);

        #pragma unroll
        for (int n2 = 0; n2 < 2; ++n2) {
            f32x4 d = {0.0f, 0.0f, 0.0f, 0.0f};
            d = __builtin_amdgcn_mfma_f32_16x16x32_bf16(a20, wl0[n2], d, 0, 0, 0);
            d = __builtin_amdgcn_mfma_f32_16x16x32_bf16(a21, wl1[n2], d, 0, 0, 0);
            #pragma unroll
            for (int i = 0; i < 4; ++i) {
                int mrow = m0 + lg * 4 + i;
                if (mrow < w)
                    out[(size_t)(lo + mrow) * D_OUT + n2 * 16 + lm] = d[i] + blv[n2];
            }
        }
    }
}

extern "C" void kernel_launch(void* const* d_in, const int* in_sizes, int n_in,
                              void* d_out, int out_size, void* d_ws, size_t ws_size,
                              hipStream_t stream) {
    const float* x_local = (const float*)d_in[0];
    const float* W_gcn   = (const float*)d_in[2];
    const float* b_gcn   = (const float*)d_in[3];
    const float* W_lin   = (const float*)d_in[10];
    const float* b_lin   = (const float*)d_in[11];
    const int*   edge_ll = (const int*)d_in[12];
    const int*   row = edge_ll;           // edge_ll[0, :]
    const int*   col = edge_ll + E_LL;    // edge_ll[1, :]

    // workspace layout (~26.9 MB)
    char* base = (char*)d_ws;
    int*    subcur     = (int*)(base + 0);            // 16,384 B (padded)
    int*    classcnt   = (int*)(base + 16384);        // 32,768 B
    float*  dinvp      = (float*)(base + 49152);      // 400,000 B
    int*    rptrg      = (int*)(base + 449536);       // 524,288 B
    uint32* classpairs = (uint32*)(base + 973824);    // 8,388,608 B
    uint32* subpairs   = (uint32*)(base + 9362432);   // 4,718,592 B
    unsigned short* xb = (unsigned short*)(base + 14081024);  // 12,800,000 B
    float* out = (float*)d_out;

    (void)hipMemsetAsync(base, 0, 16384, stream);   // subcur only

    binclass_kernel<<<NBLK1, 256, 0, stream>>>(row, col, classcnt, classpairs);
    binsub_kernel<<<NCLS * BINSUB_BPC, 256, 0, stream>>>(
        classcnt, classpairs, subcur, subpairs);
    degdinv_kernel<<<NGSB, 512, 0, stream>>>(subpairs, subcur, dinvp, rptrg);
    xbconv_kernel<<<2048, 256, 0, stream>>>(x_local, dinvp, xb);
    gather_epi_kernel<<<2 * NGSB, 512, 60416, stream>>>(
        xb, subpairs, subcur, rptrg, W_gcn, b_gcn, W_lin, b_lin, out);
}

// Round 15
// 100.720 us; speedup vs baseline: 5.2185x; 1.1144x over previous
//
#include <hip/hip_runtime.h>

#define N_L 100000
#define N_V 1000
#define D_IN 64
#define HCH 64
#define D_OUT 32
#define E_LL 1000000

#define NCLS 8
#define DST_PER_CLS 12500        // N_L / 8
#define NBLK1 1024               // binclass grid
#define BCAP 256                 // slab cap per (cls,blk): mean 122, +13 sigma
#define GW 400                   // gather-bin node width
#define HW 200                   // gather half-bin node width
#define NSB 32                   // gather bins per class
#define NGSB 256                 // total gather bins
#define SUBCAP 4608              // per-bin pair capacity (mean 3906, +11 sigma)
#define SORTCAP 2560             // per-half-bin sorted cap (mean 1953, +13 sigma)
#define SCSTRIDE 16              // subcur padding: 1 cursor per 64B line

#define L2CAP 384                // no-reject: 127 + 256 <= 383
#define L2THR 128
#define BINSUB_BPC 64            // binsub blocks per class (512 total)
#define SLABS (NBLK1 / BINSUB_BPC)   // 16 slabs per binsub block

typedef unsigned int uint32;
typedef unsigned long long u64;
typedef __attribute__((ext_vector_type(8))) short bfx8;    // 8 bf16 (4 VGPR)
typedef __attribute__((ext_vector_type(4))) float f32x4;   // MFMA C/D frag
typedef __attribute__((ext_vector_type(4))) float fvec4;
typedef __attribute__((ext_vector_type(4))) unsigned short usvec4;

__device__ inline float bf2f(unsigned short u) {
    return __uint_as_float(((uint32)u) << 16);
}
__device__ inline unsigned short f2bf(float f) {   // round-to-nearest-even
    uint32 u = __float_as_uint(f);
    u = (u + 0x7fffu + ((u >> 16) & 1u)) >> 16;
    return (unsigned short)u;
}
// LDS-only barrier: does NOT drain vmcnt (global stores stay in flight).
__device__ inline void bar_lds() {
    asm volatile("s_waitcnt lgkmcnt(0)\n\ts_barrier" ::: "memory");
}

// ---- level-1: edge scan -> per-block class slabs (ZERO global atomics) ---
__global__ __launch_bounds__(256) void binclass_kernel(
    const int* __restrict__ row, const int* __restrict__ col,
    int* __restrict__ classcnt, uint32* __restrict__ classpairs)
{
    __shared__ uint32 sbin[NCLS][BCAP];
    __shared__ int scnt[NCLS];
    if (threadIdx.x < NCLS) scnt[threadIdx.x] = 0;
    bar_lds();

    const int blk = blockIdx.x;
    const int per = (E_LL + NBLK1 - 1) / NBLK1;   // 977
    const int beg = blk * per;
    const int end = (beg + per < E_LL) ? beg + per : E_LL;
    const int lane = threadIdx.x & 63;
    const int wv = threadIdx.x >> 6;

    for (int i0 = beg; i0 < end; i0 += 256) {
        int i = i0 + threadIdx.x;
        if (i < end) {
            int c = col[i];
            int r = row[i];
            int cls = c / DST_PER_CLS;
            uint32 pack = ((uint32)r << 14) | (uint32)(c - cls * DST_PER_CLS);
            u64 act = __ballot(1);
            u64 b0 = __ballot(cls & 1);
            u64 b1 = __ballot(cls & 2);
            u64 b2 = __ballot(cls & 4);
            u64 mask = ((cls & 1) ? b0 : ~b0) & ((cls & 2) ? b1 : ~b1)
                     & ((cls & 4) ? b2 : ~b2) & act;
            int leader = __ffsll(mask) - 1;
            int rank = __popcll(mask & ((1ull << lane) - 1ull));
            int base = 0;
            if (lane == leader) base = atomicAdd(&scnt[cls], __popcll(mask));
            base = __shfl(base, leader);
            int slot = base + rank;
            if (slot < BCAP) sbin[cls][slot] = pack;   // overflow-guard
        }
    }
    bar_lds();
    for (int b = wv; b < NCLS; b += 4) {   // slab writeout (plain stores)
        int cnt = scnt[b]; if (cnt > BCAP) cnt = BCAP;
        uint32* dst = classpairs + ((size_t)b * NBLK1 + blk) * BCAP;
        for (int k = lane; k < cnt; k += 64) dst[k] = sbin[b][k];
        if (lane == 0) classcnt[b * NBLK1 + blk] = cnt;
    }
}

// ---- level-2: class slabs -> 32 gather-bins per class --------------------
__global__ __launch_bounds__(256) void binsub_kernel(
    const int* __restrict__ classcnt, const uint32* __restrict__ classpairs,
    int* __restrict__ subcur, uint32* __restrict__ subpairs)
{
    __shared__ uint32 sbin[NSB][L2CAP];
    __shared__ int scnt[NSB];
    if (threadIdx.x < NSB) scnt[threadIdx.x] = 0;
    bar_lds();

    const int cls = blockIdx.x / BINSUB_BPC;
    const int chunk = blockIdx.x % BINSUB_BPC;
    const int s0 = chunk * SLABS;
    const int lane = threadIdx.x & 63;
    const int wv = threadIdx.x >> 6;

    for (int s = s0; s < s0 + SLABS; ++s) {
        int len = classcnt[cls * NBLK1 + s];
        const uint32* cp = classpairs + ((size_t)cls * NBLK1 + s) * BCAP;
        if (threadIdx.x < len) {
            uint32 p = cp[threadIdx.x];
            int c_lo = (int)(p & 16383u);
            uint32 r = p >> 14;
            int sb = c_lo / GW;
            uint32 pack = (r << 9) | (uint32)(c_lo - sb * GW);
            u64 act = __ballot(1);
            u64 b0 = __ballot(sb & 1);
            u64 b1 = __ballot(sb & 2);
            u64 b2 = __ballot(sb & 4);
            u64 b3 = __ballot(sb & 8);
            u64 b4 = __ballot(sb & 16);
            u64 mask = ((sb & 1) ? b0 : ~b0) & ((sb & 2) ? b1 : ~b1)
                     & ((sb & 4) ? b2 : ~b2) & ((sb & 8) ? b3 : ~b3)
                     & ((sb & 16) ? b4 : ~b4) & act;
            int leader = __ffsll(mask) - 1;
            int rank = __popcll(mask & ((1ull << lane) - 1ull));
            int base = 0;
            if (lane == leader) base = atomicAdd(&scnt[sb], __popcll(mask));
            base = __shfl(base, leader);
            sbin[sb][base + rank] = pack;
        }
        bar_lds();
        for (int b = wv; b < NSB; b += 4) {
            int cnt = scnt[b];
            if (cnt >= L2THR) {
                int gb;
                int gsb = cls * NSB + b;
                if (lane == 0) gb = atomicAdd(&subcur[gsb * SCSTRIDE], cnt);
                gb = __shfl(gb, 0);
                uint32* dst = subpairs + (size_t)gsb * SUBCAP;
                for (int k = lane; k < cnt; k += 64)
                    if (gb + k < SUBCAP) dst[gb + k] = sbin[b][k];
                if (lane == 0) scnt[b] = 0;
            }
        }
        bar_lds();
    }
    for (int b = wv; b < NSB; b += 4) {   // final flush
        int cnt = scnt[b];
        if (cnt > 0) {
            int gb;
            int gsb = cls * NSB + b;
            if (lane == 0) gb = atomicAdd(&subcur[gsb * SCSTRIDE], cnt);
            gb = __shfl(gb, 0);
            uint32* dst = subpairs + (size_t)gsb * SUBCAP;
            for (int k = lane; k < cnt; k += 64)
                if (gb + k < SUBCAP) dst[gb + k] = sbin[b][k];
        }
    }
}

// ---- deg/dinv from binned data (dinv only; scan lives in gather) ---------
__global__ __launch_bounds__(512) void degdinv_kernel(
    const uint32* __restrict__ subpairs, const int* __restrict__ subcur,
    float* __restrict__ dinv)
{
    __shared__ int hcnt[512];
    const int gsb = blockIdx.x;
    const int cls = gsb >> 5;
    const int sb = gsb & 31;
    const int lo = cls * DST_PER_CLS + sb * GW;
    int w = DST_PER_CLS - sb * GW; if (w > GW) w = GW;

    hcnt[threadIdx.x] = 0;
    bar_lds();
    int cnt = subcur[gsb * SCSTRIDE]; if (cnt > SUBCAP) cnt = SUBCAP;
    const uint32* sp = subpairs + (size_t)gsb * SUBCAP;
    for (int i = threadIdx.x; i < cnt; i += 512)
        atomicAdd(&hcnt[sp[i] & 511u], 1);
    bar_lds();
    if (threadIdx.x < w) {
        int d = hcnt[threadIdx.x];
        dinv[lo + threadIdx.x] = (d > 0) ? rsqrtf((float)d) : 0.0f;
    }
}

// ---- xb[r,:] = bf16(x[r,:] * dinv[r]) ------------------------------------
__global__ void xbconv_kernel(const float* __restrict__ x,
                              const float* __restrict__ dinv,
                              unsigned short* __restrict__ xb) {
    int n4 = N_L * D_IN / 4;
    int idx = blockIdx.x * blockDim.x + threadIdx.x;
    int stride = gridDim.x * blockDim.x;
    for (; idx < n4; idx += stride) {
        fvec4 v = ((const fvec4*)x)[idx];
        float d = dinv[idx >> 4];
        usvec4 o;
        o.x = f2bf(v.x * d);
        o.y = f2bf(v.y * d);
        o.z = f2bf(v.z * d);
        o.w = f2bf(v.w * d);
        ((usvec4*)xb)[idx] = o;
    }
}

// ---- gather + fused epilogue: FLAT edge-parallel accumulation ------------
// 512 blocks (2 per bin) x 512 threads. Each wave streams a contiguous
// slice of the node-sorted edge list at full ILP-8 (no per-node tails);
// node transitions are wave-uniform scalar branches. Interior nodes flush
// with a plain LDS write; <=2 boundary nodes/wave combine via f32 partials.
__global__ __launch_bounds__(512) void gather_epi_kernel(
    const unsigned short* __restrict__ xb,
    const uint32* __restrict__ subpairs, const int* __restrict__ subcur,
    const float* __restrict__ Wg, const float* __restrict__ bg,
    const float* __restrict__ Wl, const float* __restrict__ bl,
    float* __restrict__ out)
{
    extern __shared__ char smem[];
    unsigned short* hacc  = (unsigned short*)smem;            // [208][72] bf16
    unsigned short* hbufp = (unsigned short*)(smem + 29952);  // [8][16][72]
    uint32* sorted = (uint32*)(smem + 48384);                 // [SORTCAP]
    int* hist  = (int*)(smem + 58624);                        // [256]
    int* scn   = (int*)(smem + 59648);                        // [256]
    int* cur   = (int*)(smem + 60672);                        // [256]
    float* bpart = (float*)(smem + 61696);                    // [16][64] f32
    int* bnode = (int*)(smem + 65792);                        // [16]

    const int gsb = blockIdx.x >> 1;
    const int hb  = blockIdx.x & 1;
    const int cls = gsb >> 5;
    const int sb  = gsb & 31;
    const int lo_bin = cls * DST_PER_CLS + sb * GW;
    int wbin = DST_PER_CLS - sb * GW; if (wbin > GW) wbin = GW;  // 400 or 100
    const int lo_node = hb * HW;
    int w = wbin - lo_node; if (w > HW) w = HW; if (w < 0) w = 0;
    const int lo = lo_bin + lo_node;

    const int tid = threadIdx.x;
    const int lane = tid & 63;
    const int wv = tid >> 6;     // 0..7

    int cnt = subcur[gsb * SCSTRIDE]; if (cnt > SUBCAP) cnt = SUBCAP;
    const uint32* sp = subpairs + (size_t)gsb * SUBCAP;

    // init: zero hacc + hist, bnode = -1
    {
        uint32* hz = (uint32*)hacc;
        for (int i = tid; i < 208 * 36; i += 512) hz[i] = 0u;
        if (tid < 256) hist[tid] = 0;
        if (tid < 16) bnode[tid] = -1;
    }
    bar_lds();

    // (1) histogram my half
    for (int i = tid; i < cnt; i += 512) {
        int cl = (int)(sp[i] & 511u) - lo_node;
        if (cl >= 0 && cl < w) atomicAdd(&hist[cl], 1);
    }
    bar_lds();

    // (2) exclusive scan over 256
    int v = (tid < 256) ? hist[tid] : 0;
    if (tid < 256) scn[tid] = v;
    bar_lds();
    for (int ofs = 1; ofs < 256; ofs <<= 1) {
        int add = (tid < 256 && tid >= ofs) ? scn[tid - ofs] : 0;
        bar_lds();
        if (tid < 256) scn[tid] += add;
        bar_lds();
    }
    if (tid < 256) cur[tid] = scn[tid] - v;
    bar_lds();

    // (3) place: sorted[pos] = (r << 8) | cl
    for (int i = tid; i < cnt; i += 512) {
        uint32 p = sp[i];
        int cl = (int)(p & 511u) - lo_node;
        if (cl >= 0 && cl < w) {
            int pos = atomicAdd(&cur[cl], 1);
            if (pos < SORTCAP) sorted[pos] = ((p >> 9) << 8) | (uint32)cl;
        }
    }
    bar_lds();

    // (4) flat edge-parallel accumulate (ILP-8, wave-uniform node tracking)
    int ch = scn[255]; if (ch > SORTCAP) ch = SORTCAP;
    {
        int a = (ch * wv) >> 3;
        int b = (ch * (wv + 1)) >> 3;
        if (a < b) {
            float acc = 0.0f;
            int curn = (int)(sorted[a] & 255u);
            bool firstopen = true;

#define GSTEP(EK, VK)                                                        \
            {                                                                \
                int nk = (int)((EK) & 255u);                                 \
                if (nk != curn) {                                            \
                    if (firstopen) {                                         \
                        bpart[(2 * wv) * 64 + lane] = acc;                   \
                        if (lane == 0) bnode[2 * wv] = curn;                 \
                        firstopen = false;                                   \
                    } else {                                                 \
                        hacc[curn * 72 + lane] =                             \
                            f2bf(acc * rsqrtf((float)hist[curn]));           \
                    }                                                        \
                    acc = 0.0f; curn = nk;                                   \
                }                                                            \
                acc += (VK);                                                 \
            }

            int j = a;
            for (; j + 8 <= b; j += 8) {
                uint32 e0 = sorted[j + 0], e1 = sorted[j + 1];
                uint32 e2 = sorted[j + 2], e3 = sorted[j + 3];
                uint32 e4 = sorted[j + 4], e5 = sorted[j + 5];
                uint32 e6 = sorted[j + 6], e7 = sorted[j + 7];
                float v0 = bf2f(xb[(size_t)(e0 >> 8) * D_IN + lane]);
                float v1 = bf2f(xb[(size_t)(e1 >> 8) * D_IN + lane]);
                float v2 = bf2f(xb[(size_t)(e2 >> 8) * D_IN + lane]);
                float v3 = bf2f(xb[(size_t)(e3 >> 8) * D_IN + lane]);
                float v4 = bf2f(xb[(size_t)(e4 >> 8) * D_IN + lane]);
                float v5 = bf2f(xb[(size_t)(e5 >> 8) * D_IN + lane]);
                float v6 = bf2f(xb[(size_t)(e6 >> 8) * D_IN + lane]);
                float v7 = bf2f(xb[(size_t)(e7 >> 8) * D_IN + lane]);
                GSTEP(e0, v0) GSTEP(e1, v1) GSTEP(e2, v2) GSTEP(e3, v3)
                GSTEP(e4, v4) GSTEP(e5, v5) GSTEP(e6, v6) GSTEP(e7, v7)
            }
            for (; j < b; ++j) {
                uint32 e = sorted[j];
                float vv = bf2f(xb[(size_t)(e >> 8) * D_IN + lane]);
                GSTEP(e, vv)
            }
#undef GSTEP
            // close the open node -> boundary partial
            if (firstopen) {
                bpart[(2 * wv) * 64 + lane] = acc;
                if (lane == 0) bnode[2 * wv] = curn;
            } else {
                bpart[(2 * wv + 1) * 64 + lane] = acc;
                if (lane == 0) bnode[2 * wv + 1] = curn;
            }
        }
    }
    bar_lds();

    // boundary combine (one wave)
    if (wv == 0) {
        for (int e2 = 0; e2 < 16; ++e2) {
            int n = bnode[e2];
            if (n < 0) continue;
            bool first = true;
            for (int f = 0; f < e2; ++f)
                if (bnode[f] == n) { first = false; break; }
            if (!first) continue;
            float s = bpart[e2 * 64 + lane];
            for (int f = e2 + 1; f < 16; ++f)
                if (bnode[f] == n) s += bpart[f * 64 + lane];
            hacc[n * 72 + lane] = f2bf(s * rsqrtf((float)hist[n]));
        }
    }
    bar_lds();

    if (w == 0) return;   // empty half of the tail bin

    // (5) MFMA epilogue
    const int lm = lane & 15, lg = lane >> 4, kseg = lg * 8;

    bfx8 wg0[4], wg1[4], wl0[2], wl1[2];
    #pragma unroll
    for (int n = 0; n < 4; ++n) {
        #pragma unroll
        for (int jj = 0; jj < 8; ++jj) {
            wg0[n][jj] = (short)f2bf(Wg[(kseg + jj) * HCH + n * 16 + lm]);
            wg1[n][jj] = (short)f2bf(Wg[(32 + kseg + jj) * HCH + n * 16 + lm]);
        }
    }
    #pragma unroll
    for (int n = 0; n < 2; ++n) {
        #pragma unroll
        for (int jj = 0; jj < 8; ++jj) {
            wl0[n][jj] = (short)f2bf(Wl[(kseg + jj) * D_OUT + n * 16 + lm]);
            wl1[n][jj] = (short)f2bf(Wl[(32 + kseg + jj) * D_OUT + n * 16 + lm]);
        }
    }
    float bgv[4], blv[2];
    #pragma unroll
    for (int n = 0; n < 4; ++n) bgv[n] = bg[n * 16 + lm];
    #pragma unroll
    for (int n = 0; n < 2; ++n) blv[n] = bl[n * 16 + lm];

    const int ntile = (w + 15) >> 4;   // <= 13
    for (int t = wv; t < ntile; t += 8) {
        const int m0 = t * 16;
        const int arow = m0 + lm;       // rows >= w read zeros; masked on store
        const unsigned short* fr = hacc + arow * 72;
        bfx8 a0 = *(const bfx8*)(fr + kseg);
        bfx8 a1 = *(const bfx8*)(fr + 32 + kseg);

        unsigned short* hbw = hbufp + wv * (16 * 72);
        #pragma unroll
        for (int n = 0; n < 4; ++n) {
            f32x4 cacc = {0.0f, 0.0f, 0.0f, 0.0f};
            cacc = __builtin_amdgcn_mfma_f32_16x16x32_bf16(a0, wg0[n], cacc, 0, 0, 0);
            cacc = __builtin_amdgcn_mfma_f32_16x16x32_bf16(a1, wg1[n], cacc, 0, 0, 0);
            #pragma unroll
            for (int i = 0; i < 4; ++i) {
                float h = fmaxf(cacc[i] + bgv[n], 0.0f);
                hbw[(lg * 4 + i) * 72 + n * 16 + lm] = f2bf(h);
            }
        }
        bfx8 a20 = *(const bfx8*)(hbw + lm * 72 + kseg);
        bfx8 a21 = *(const bfx8*)(hbw + lm * 72 + 32 + kseg);

        #pragma unroll
        for (int n2 = 0; n2 < 2; ++n2) {
            f32x4 d = {0.0f, 0.0f, 0.0f, 0.0f};
            d = __builtin_amdgcn_mfma_f32_16x16x32_bf16(a20, wl0[n2], d, 0, 0, 0);
            d = __builtin_amdgcn_mfma_f32_16x16x32_bf16(a21, wl1[n2], d, 0, 0, 0);
            #pragma unroll
            for (int i = 0; i < 4; ++i) {
                int mrow = m0 + lg * 4 + i;
                if (mrow < w)
                    out[(size_t)(lo + mrow) * D_OUT + n2 * 16 + lm] = d[i] + blv[n2];
            }
        }
    }
}

extern "C" void kernel_launch(void* const* d_in, const int* in_sizes, int n_in,
                              void* d_out, int out_size, void* d_ws, size_t ws_size,
                              hipStream_t stream) {
    const float* x_local = (const float*)d_in[0];
    const float* W_gcn   = (const float*)d_in[2];
    const float* b_gcn   = (const float*)d_in[3];
    const float* W_lin   = (const float*)d_in[10];
    const float* b_lin   = (const float*)d_in[11];
    const int*   edge_ll = (const int*)d_in[12];
    const int*   row = edge_ll;           // edge_ll[0, :]
    const int*   col = edge_ll + E_LL;    // edge_ll[1, :]

    // workspace layout (~26.4 MB)
    char* base = (char*)d_ws;
    int*    subcur     = (int*)(base + 0);            // 16,384 B (padded)
    int*    classcnt   = (int*)(base + 16384);        // 32,768 B
    float*  dinvp      = (float*)(base + 49152);      // 400,000 B
    uint32* classpairs = (uint32*)(base + 449536);    // 8,388,608 B
    uint32* subpairs   = (uint32*)(base + 8838144);   // 4,718,592 B
    unsigned short* xb = (unsigned short*)(base + 13556736);  // 12,800,000 B
    float* out = (float*)d_out;

    (void)hipMemsetAsync(base, 0, 16384, stream);   // subcur only

    binclass_kernel<<<NBLK1, 256, 0, stream>>>(row, col, classcnt, classpairs);
    binsub_kernel<<<NCLS * BINSUB_BPC, 256, 0, stream>>>(
        classcnt, classpairs, subcur, subpairs);
    degdinv_kernel<<<NGSB, 512, 0, stream>>>(subpairs, subcur, dinvp);
    xbconv_kernel<<<2048, 256, 0, stream>>>(x_local, dinvp, xb);
    gather_epi_kernel<<<2 * NGSB, 512, 65856, stream>>>(
        xb, subpairs, subcur, W_gcn, b_gcn, W_lin, b_lin, out);
}